// Round 7
// baseline (1308.157 us; speedup 1.0000x reference)
//
#include <hip/hip_runtime.h>
#include <hip/hip_fp16.h>

#define NN 20000
#define EE 320000

__device__ __forceinline__ float silu_f(float x) {
    return x / (1.0f + __expf(-x));
}

__device__ __forceinline__ unsigned pk_h2(float a, float b) {
    __half2 h = __floats2half2_rn(a, b);
    return *reinterpret_cast<unsigned*>(&h);
}

// ---------------- Kernel 1: node up-projection (16 nodes/block) ----------------
// dmajor=1: up2[n] = [ s(0..63) | evx(64..127) | evy(128..191) | evz(192..255) ]
// dmajor=0: legacy interleaved [ s(0..63) | ev[m][d] at 64+3m+d ]  (fallback path)
__global__ __launch_bounds__(256) void up_kernel(
    const float* __restrict__ nf, const float* __restrict__ Wus,
    const float* __restrict__ Wuv, float* __restrict__ up, int dmajor)
{
    __shared__ float sWs[64 * 64];
    __shared__ float sWv[64 * 64];
    int tid = threadIdx.x;
    for (int i = tid; i < 64 * 64; i += 256) { sWs[i] = Wus[i]; sWv[i] = Wuv[i]; }
    __syncthreads();
    int lane = tid & 63, wv = tid >> 6;
    for (int it = 0; it < 4; it++) {
        int n = blockIdx.x * 16 + wv * 4 + it;          // 1250*16 = 20000 exact
        const float* row = nf + (size_t)n * 256;
        float s  = row[lane];
        float v0 = row[64 + lane * 3 + 0];
        float v1 = row[64 + lane * 3 + 1];
        float v2 = row[64 + lane * 3 + 2];
        float as = 0.f, a0 = 0.f, a1 = 0.f, a2 = 0.f;
        #pragma unroll 8
        for (int m = 0; m < 64; m++) {
            float sm = __shfl(s, m);
            float b0 = __shfl(v0, m), b1 = __shfl(v1, m), b2 = __shfl(v2, m);
            float w_s = sWs[m * 64 + lane];
            float w_v = sWv[m * 64 + lane];
            as += sm * w_s;
            a0 += b0 * w_v; a1 += b1 * w_v; a2 += b2 * w_v;
        }
        float* o = up + (size_t)n * 256;
        if (dmajor) {
            o[lane]       = as * 0.125f;
            o[64  + lane] = a0 * 0.125f;
            o[128 + lane] = a1 * 0.125f;
            o[192 + lane] = a2 * 0.125f;
        } else {
            o[lane] = as * 0.125f;
            o[64 + lane * 3 + 0] = a0 * 0.125f;
            o[64 + lane * 3 + 1] = a1 * 0.125f;
            o[64 + lane * 3 + 2] = a2 * 0.125f;
        }
    }
}

// ---------------- Kernel 2: edge MLP -> mix (fp16, EDGE order, no CSR) ----------------
// Thread-per-edge; fp16 hidden in thread-private LDS columns; zero barriers.
// Each thread stores its 16-feature chunk as 2x uint4 (32B contiguous).
// LDS = 32 KiB -> 4 blocks/CU (16 waves/CU).
__global__ __launch_bounds__(256) void mlp_kernel(
    const float* __restrict__ radial,
    const float* __restrict__ w1, const float* __restrict__ w2,
    const float* __restrict__ w3, const float* __restrict__ wo,
    __half* __restrict__ mix)
{
    __shared__ __half2 hL[32 * 256];   // 32 KiB, thread-private columns

    int tid = threadIdx.x;
    int e = blockIdx.x * 256 + tid;    // 1250*256 = EE exact
    float4 ra = *(const float4*)(radial + (size_t)e * 8);
    float4 rb = *(const float4*)(radial + (size_t)e * 8 + 4);

    // layer 1: 8 -> 64
    {
        float a[64];
        #pragma unroll
        for (int j = 0; j < 64; j++) {
            float acc = ra.x * w1[j]       + ra.y * w1[64 + j]
                      + ra.z * w1[128 + j] + ra.w * w1[192 + j]
                      + rb.x * w1[256 + j] + rb.y * w1[320 + j]
                      + rb.z * w1[384 + j] + rb.w * w1[448 + j];
            a[j] = silu_f(acc * 0.35355339059327373f);
        }
        #pragma unroll
        for (int jp = 0; jp < 32; jp++)
            hL[jp * 256 + tid] = __floats2half2_rn(a[2 * jp], a[2 * jp + 1]);
    }
    // layer 2: 64 -> 64
    {
        float acc[64];
        #pragma unroll
        for (int j = 0; j < 64; j++) acc[j] = 0.f;
        #pragma unroll 2
        for (int kp = 0; kp < 32; kp++) {
            float2 hf = __half22float2(hL[kp * 256 + tid]);
            const float* wr0 = w2 + (size_t)(2 * kp) * 64;
            const float* wr1 = w2 + (size_t)(2 * kp + 1) * 64;
            #pragma unroll
            for (int j = 0; j < 64; j++) acc[j] += hf.x * wr0[j] + hf.y * wr1[j];
        }
        #pragma unroll
        for (int jp = 0; jp < 32; jp++)
            hL[jp * 256 + tid] = __floats2half2_rn(silu_f(acc[2 * jp] * 0.125f),
                                                   silu_f(acc[2 * jp + 1] * 0.125f));
    }
    // layer 3: 64 -> 64
    {
        float acc[64];
        #pragma unroll
        for (int j = 0; j < 64; j++) acc[j] = 0.f;
        #pragma unroll 2
        for (int kp = 0; kp < 32; kp++) {
            float2 hf = __half22float2(hL[kp * 256 + tid]);
            const float* wr0 = w3 + (size_t)(2 * kp) * 64;
            const float* wr1 = w3 + (size_t)(2 * kp + 1) * 64;
            #pragma unroll
            for (int j = 0; j < 64; j++) acc[j] += hf.x * wr0[j] + hf.y * wr1[j];
        }
        #pragma unroll
        for (int jp = 0; jp < 32; jp++)
            hL[jp * 256 + tid] = __floats2half2_rn(silu_f(acc[2 * jp] * 0.125f),
                                                   silu_f(acc[2 * jp + 1] * 0.125f));
    }

    // output layer: 64 -> 256 in 16 chunks of 16; direct packed stores
    for (int c = 0; c < 16; c++) {
        float ao[16];
        #pragma unroll
        for (int j = 0; j < 16; j++) ao[j] = 0.f;
        #pragma unroll 4
        for (int kp = 0; kp < 32; kp++) {
            float2 hf = __half22float2(hL[kp * 256 + tid]);
            const float* wr0 = wo + (size_t)(2 * kp) * 256 + c * 16;
            const float* wr1 = wo + (size_t)(2 * kp + 1) * 256 + c * 16;
            #pragma unroll
            for (int j = 0; j < 16; j++)
                ao[j] += hf.x * wr0[j] + hf.y * wr1[j];
        }
        #pragma unroll
        for (int j = 0; j < 16; j++) ao[j] *= 0.125f;
        uint4* dst = reinterpret_cast<uint4*>(mix + (size_t)e * 256 + c * 16);
        dst[0] = make_uint4(pk_h2(ao[0], ao[1]),  pk_h2(ao[2], ao[3]),
                            pk_h2(ao[4], ao[5]),  pk_h2(ao[6], ao[7]));
        dst[1] = make_uint4(pk_h2(ao[8], ao[9]),  pk_h2(ao[10], ao[11]),
                            pk_h2(ao[12], ao[13]), pk_h2(ao[14], ao[15]));
    }
}

// ---------------- Kernel 3: wave-per-edge atomic scatter (no LDS, no barriers) ----------------
// Per edge: 4 coalesced 128B mix loads + 4 coalesced up-row loads + 8 atomic
// wave-instructions, each a contiguous 256B span of the receiver's agg row.
__global__ __launch_bounds__(256) void scatter_kernel(
    const int* __restrict__ senders, const int* __restrict__ receivers,
    const float* __restrict__ vectors, const __half* __restrict__ mix,
    const float* __restrict__ up2, float* __restrict__ agg)
{
    int lane = threadIdx.x & 63;
    int wid  = (blockIdx.x * 256 + threadIdx.x) >> 6;   // global wave id
    int nw   = gridDim.x * 4;
    const float SQ3 = 1.7320508075688772f;

    for (int e = wid; e < EE; e += nw) {
        int snd = senders[e];
        int rcv = receivers[e];
        if ((unsigned)snd >= (unsigned)NN) snd = 0;
        if ((unsigned)rcv >= (unsigned)NN) rcv = 0;
        float vx = vectors[(size_t)e * 3 + 0];
        float vy = vectors[(size_t)e * 3 + 1];
        float vz = vectors[(size_t)e * 3 + 2];
        float l2 = vx * vx + vy * vy + vz * vz;
        float il   = (l2 > 0.f) ? rsqrtf(l2) : 0.f;
        float mask = (l2 > 0.f) ? 1.f : 0.f;

        const __half* mr = mix + (size_t)e * 256;
        float mA = __half2float(mr[lane])        * mask;
        float mB = __half2float(mr[64  + lane])  * mask;
        float mC = __half2float(mr[128 + lane])  * mask;
        float mD = __half2float(mr[192 + lane])  * mask;

        const float* u = up2 + (size_t)snd * 256;
        float s  = u[lane];
        float ex = u[64 + lane], ey = u[128 + lane], ez = u[192 + lane];

        float* ar = agg + (size_t)rcv * 512;
        atomicAdd(ar + lane,        s * mA);
        float tps = (ex * vx + ey * vy + ez * vz) * il;
        atomicAdd(ar + 64  + lane,  tps * mB);
        atomicAdd(ar + 128 + lane,  ex * mC);
        atomicAdd(ar + 192 + lane,  ey * mC);
        atomicAdd(ar + 256 + lane,  ez * mC);
        float yx = SQ3 * vx * il, yy = SQ3 * vy * il, yz = SQ3 * vz * il;
        float sD = s * mD;
        atomicAdd(ar + 320 + lane,  sD * yx);
        atomicAdd(ar + 384 + lane,  sD * yy);
        atomicAdd(ar + 448 + lane,  sD * yz);
    }
}

// ---------------- Kernel 4: node tail (down + skip + gate + relu) ----------------
__global__ __launch_bounds__(256) void node_kernel(
    const float* __restrict__ nf, const int* __restrict__ specie,
    const float* __restrict__ Wds, const float* __restrict__ Wdv,
    const float* __restrict__ Wss, const float* __restrict__ Wsv,
    const float* __restrict__ agg, float* __restrict__ out)
{
    __shared__ float sDs[128 * 128];  // 64 KiB
    __shared__ float sDv[128 * 64];   // 32 KiB
    int tid = threadIdx.x;
    for (int i = tid; i < 128 * 128; i += 256) sDs[i] = Wds[i];
    for (int i = tid; i < 128 * 64; i += 256) sDv[i] = Wdv[i];
    __syncthreads();
    int lane = tid & 63, wv = tid >> 6;
    for (int it = 0; it < 4; it++) {
        int n = blockIdx.x * 16 + wv * 4 + it;
        const float* arow = agg + (size_t)n * 512;
        const float inv_nei = 0.25f;
        float as0 = arow[lane] * inv_nei;
        float as1 = arow[64 + lane] * inv_nei;
        float av00 = arow[128 + lane] * inv_nei;
        float av01 = arow[192 + lane] * inv_nei;
        float av02 = arow[256 + lane] * inv_nei;
        float av10 = arow[320 + lane] * inv_nei;
        float av11 = arow[384 + lane] * inv_nei;
        float av12 = arow[448 + lane] * inv_nei;
        const float* row = nf + (size_t)n * 256;
        float s   = row[lane];
        float vv0 = row[64 + lane * 3 + 0];
        float vv1 = row[64 + lane * 3 + 1];
        float vv2 = row[64 + lane * 3 + 2];

        float f0 = 0.f, f1 = 0.f, fv0 = 0.f, fv1 = 0.f, fv2 = 0.f;
        #pragma unroll 8
        for (int m = 0; m < 64; m++) {
            float am = __shfl(as0, m);
            f0 += am * sDs[m * 128 + lane];
            f1 += am * sDs[m * 128 + 64 + lane];
            float b0 = __shfl(av00, m), b1 = __shfl(av01, m), b2 = __shfl(av02, m);
            float wd = sDv[m * 64 + lane];
            fv0 += b0 * wd; fv1 += b1 * wd; fv2 += b2 * wd;
        }
        #pragma unroll 8
        for (int m = 0; m < 64; m++) {
            float am = __shfl(as1, m);
            f0 += am * sDs[(64 + m) * 128 + lane];
            f1 += am * sDs[(64 + m) * 128 + 64 + lane];
            float b0 = __shfl(av10, m), b1 = __shfl(av11, m), b2 = __shfl(av12, m);
            float wd = sDv[(64 + m) * 64 + lane];
            fv0 += b0 * wd; fv1 += b1 * wd; fv2 += b2 * wd;
        }
        const float inv2m = 0.08838834764831845f;
        f0 *= inv2m; f1 *= inv2m; fv0 *= inv2m; fv1 *= inv2m; fv2 *= inv2m;

        int sp = specie[n];
        if ((unsigned)sp >= 5u) sp = 0;
        const float* Ws = Wss + (size_t)sp * 64 * 128;
        const float* Wv = Wsv + (size_t)sp * 64 * 64;
        float g0 = 0.f, g1 = 0.f, h0 = 0.f, h1 = 0.f, h2 = 0.f;
        #pragma unroll 4
        for (int m = 0; m < 64; m++) {
            float sm = __shfl(s, m);
            g0 += sm * Ws[m * 128 + lane];
            g1 += sm * Ws[m * 128 + 64 + lane];
            float b0 = __shfl(vv0, m), b1 = __shfl(vv1, m), b2 = __shfl(vv2, m);
            float wsk = Wv[m * 64 + lane];
            h0 += b0 * wsk; h1 += b1 * wsk; h2 += b2 * wsk;
        }
        f0 += g0 * 0.125f; f1 += g1 * 0.125f;
        fv0 += h0 * 0.125f; fv1 += h1 * 0.125f; fv2 += h2 * 0.125f;

        float gs   = silu_f(f0);
        float gate = silu_f(f1);
        float* orow = out + (size_t)n * 256;
        orow[lane] = fmaxf(gs, 0.f);
        orow[64 + lane * 3 + 0] = fmaxf(gate * fv0, 0.f);
        orow[64 + lane * 3 + 1] = fmaxf(gate * fv1, 0.f);
        orow[64 + lane * 3 + 2] = fmaxf(gate * fv2, 0.f);
    }
}

// ---------------- Fallback: round-3 fused edge kernel (interleaved up layout) ----------------
__global__ __launch_bounds__(256) void edge_kernel_fb(
    const float* __restrict__ vectors, const float* __restrict__ radial,
    const int* __restrict__ senders, const int* __restrict__ receivers,
    const float* __restrict__ w1, const float* __restrict__ w2,
    const float* __restrict__ w3, const float* __restrict__ wo,
    const float* __restrict__ up, float* __restrict__ agg)
{
    __shared__ __half2 hL[32 * 256];
    __shared__ float   T[16 * 256];
    __shared__ float   sVec[256 * 3];
    __shared__ int     sSnd[256];
    __shared__ int     sRcv[256];

    int tid = threadIdx.x;
    int e = blockIdx.x * 256 + tid;
    int snd = senders[e];
    int rcv = receivers[e];
    if ((unsigned)snd >= (unsigned)NN) snd = 0;
    if ((unsigned)rcv >= (unsigned)NN) rcv = 0;
    float4 ra = *(const float4*)(radial + (size_t)e * 8);
    float4 rb = *(const float4*)(radial + (size_t)e * 8 + 4);
    float vx = vectors[(size_t)e * 3 + 0];
    float vy = vectors[(size_t)e * 3 + 1];
    float vz = vectors[(size_t)e * 3 + 2];
    sSnd[tid] = snd; sRcv[tid] = rcv;
    sVec[tid * 3 + 0] = vx; sVec[tid * 3 + 1] = vy; sVec[tid * 3 + 2] = vz;
    float len2 = vx * vx + vy * vy + vz * vz;
    float mask = (len2 > 0.f) ? 1.f : 0.f;

    {
        float a[64];
        #pragma unroll
        for (int j = 0; j < 64; j++) {
            float acc = ra.x * w1[j]       + ra.y * w1[64 + j]
                      + ra.z * w1[128 + j] + ra.w * w1[192 + j]
                      + rb.x * w1[256 + j] + rb.y * w1[320 + j]
                      + rb.z * w1[384 + j] + rb.w * w1[448 + j];
            a[j] = silu_f(acc * 0.35355339059327373f);
        }
        #pragma unroll
        for (int jp = 0; jp < 32; jp++)
            hL[jp * 256 + tid] = __floats2half2_rn(a[2 * jp], a[2 * jp + 1]);
    }
    {
        float acc[64];
        #pragma unroll
        for (int j = 0; j < 64; j++) acc[j] = 0.f;
        #pragma unroll 2
        for (int kp = 0; kp < 32; kp++) {
            float2 hf = __half22float2(hL[kp * 256 + tid]);
            const float* wr0 = w2 + (size_t)(2 * kp) * 64;
            const float* wr1 = w2 + (size_t)(2 * kp + 1) * 64;
            #pragma unroll
            for (int j = 0; j < 64; j++) acc[j] += hf.x * wr0[j] + hf.y * wr1[j];
        }
        #pragma unroll
        for (int jp = 0; jp < 32; jp++)
            hL[jp * 256 + tid] = __floats2half2_rn(silu_f(acc[2 * jp] * 0.125f),
                                                   silu_f(acc[2 * jp + 1] * 0.125f));
    }
    {
        float acc[64];
        #pragma unroll
        for (int j = 0; j < 64; j++) acc[j] = 0.f;
        #pragma unroll 2
        for (int kp = 0; kp < 32; kp++) {
            float2 hf = __half22float2(hL[kp * 256 + tid]);
            const float* wr0 = w3 + (size_t)(2 * kp) * 64;
            const float* wr1 = w3 + (size_t)(2 * kp + 1) * 64;
            #pragma unroll
            for (int j = 0; j < 64; j++) acc[j] += hf.x * wr0[j] + hf.y * wr1[j];
        }
        #pragma unroll
        for (int jp = 0; jp < 32; jp++)
            hL[jp * 256 + tid] = __floats2half2_rn(silu_f(acc[2 * jp] * 0.125f),
                                                   silu_f(acc[2 * jp + 1] * 0.125f));
    }

    int lane  = tid & 63;
    int wbase = tid & 192;
    int f = lane & 15;
    int g = lane >> 4;

    #define COMPUTE_CHUNK(c, ao)                                                \
        {                                                                       \
            _Pragma("unroll")                                                   \
            for (int j = 0; j < 16; j++) ao[j] = 0.f;                           \
            _Pragma("unroll 4")                                                 \
            for (int kp = 0; kp < 32; kp++) {                                   \
                float2 hf = __half22float2(hL[kp * 256 + tid]);                 \
                const float* wr0 = wo + (size_t)(2 * kp) * 256 + (c) * 16;      \
                const float* wr1 = wo + (size_t)(2 * kp + 1) * 256 + (c) * 16;  \
                _Pragma("unroll")                                               \
                for (int j = 0; j < 16; j++)                                    \
                    ao[j] += hf.x * wr0[j] + hf.y * wr1[j];                     \
            }                                                                   \
            _Pragma("unroll")                                                   \
            for (int j = 0; j < 16; j++) ao[j] *= 0.125f * mask;                \
        }

    #define WRITE_T(ao)                                                         \
        __syncthreads();                                                        \
        _Pragma("unroll")                                                       \
        for (int j = 0; j < 16; j++) T[j * 256 + (tid ^ (2 * j))] = ao[j];      \
        __syncthreads();

    for (int c = 0; c < 4; c++) {
        float ao[16];
        COMPUTE_CHUNK(c, ao)
        WRITE_T(ao)
        for (int el = 0; el < 16; el++) {
            int col = wbase + el * 4 + g;
            int s_ = sSnd[col], rc = sRcv[col];
            float mx = T[f * 256 + (col ^ (2 * f))];
            int jf = c * 16 + f;
            atomicAdd(agg + (size_t)rc * 512 + jf, up[(size_t)s_ * 256 + jf] * mx);
        }
    }
    for (int c = 4; c < 8; c++) {
        float ao[16];
        COMPUTE_CHUNK(c, ao)
        WRITE_T(ao)
        for (int el = 0; el < 16; el++) {
            int col = wbase + el * 4 + g;
            int s_ = sSnd[col], rc = sRcv[col];
            float wx = sVec[col * 3 + 0], wy = sVec[col * 3 + 1], wz = sVec[col * 3 + 2];
            float l2 = wx * wx + wy * wy + wz * wz;
            float il = (l2 > 0.f) ? rsqrtf(l2) : 0.f;
            float mx = T[f * 256 + (col ^ (2 * f))];
            int m = (c - 4) * 16 + f;
            const float* ev = up + (size_t)s_ * 256 + 64 + m * 3;
            float dot = ev[0] * wx + ev[1] * wy + ev[2] * wz;
            atomicAdd(agg + (size_t)rc * 512 + 64 + m, dot * il * mx);
        }
    }
    for (int c = 8; c < 12; c++) {
        float ao[16];
        COMPUTE_CHUNK(c, ao)
        WRITE_T(ao)
        for (int el = 0; el < 16; el++) {
            int col = wbase + el * 4 + g;
            int s_ = sSnd[col], rc = sRcv[col];
            float mx = T[f * 256 + (col ^ (2 * f))];
            int m = (c - 8) * 16 + f;
            const float* ev = up + (size_t)s_ * 256 + 64 + m * 3;
            float* ag = agg + (size_t)rc * 512 + 128 + m;
            atomicAdd(ag + 0,   ev[0] * mx);
            atomicAdd(ag + 64,  ev[1] * mx);
            atomicAdd(ag + 128, ev[2] * mx);
        }
    }
    for (int c = 12; c < 16; c++) {
        float ao[16];
        COMPUTE_CHUNK(c, ao)
        WRITE_T(ao)
        for (int el = 0; el < 16; el++) {
            int col = wbase + el * 4 + g;
            int s_ = sSnd[col], rc = sRcv[col];
            float wx = sVec[col * 3 + 0], wy = sVec[col * 3 + 1], wz = sVec[col * 3 + 2];
            float l2 = wx * wx + wy * wy + wz * wz;
            float il = (l2 > 0.f) ? rsqrtf(l2) : 0.f;
            float mx = T[f * 256 + (col ^ (2 * f))];
            int m = (c - 12) * 16 + f;
            float sc = up[(size_t)s_ * 256 + m] * 1.7320508075688772f * il * mx;
            float* ag = agg + (size_t)rc * 512 + 320 + m;
            atomicAdd(ag + 0,   sc * wx);
            atomicAdd(ag + 64,  sc * wy);
            atomicAdd(ag + 128, sc * wz);
        }
    }
    #undef COMPUTE_CHUNK
    #undef WRITE_T
}

extern "C" void kernel_launch(void* const* d_in, const int* in_sizes, int n_in,
                              void* d_out, int out_size, void* d_ws, size_t ws_size,
                              hipStream_t stream) {
    const float* vectors     = (const float*)d_in[0];
    const float* node_feats  = (const float*)d_in[1];
    const int*   node_specie = (const int*)d_in[2];
    const float* radial      = (const float*)d_in[3];
    const int*   senders     = (const int*)d_in[4];
    const int*   receivers   = (const int*)d_in[5];
    const float* W_up_s      = (const float*)d_in[6];
    const float* W_up_v      = (const float*)d_in[7];
    const float* mlp_w1      = (const float*)d_in[8];
    const float* mlp_w2      = (const float*)d_in[9];
    const float* mlp_w3      = (const float*)d_in[10];
    const float* mlp_wo      = (const float*)d_in[11];
    const float* W_skip_s    = (const float*)d_in[12];
    const float* W_skip_v    = (const float*)d_in[13];
    const float* W_down_s    = (const float*)d_in[14];
    const float* W_down_v    = (const float*)d_in[15];
    float* out = (float*)d_out;

    // workspace layout: up | agg | mix (256B-aligned)
    float* up  = (float*)d_ws;                       // NN*256 f32  = 20.48 MB
    float* agg = up + (size_t)NN * 256;              // NN*512 f32  = 40.96 MB
    uintptr_t mix_addr = ((uintptr_t)(agg + (size_t)NN * 512) + 255) & ~(uintptr_t)255;
    __half* mix = (__half*)mix_addr;                 // EE*256 fp16 = 163.84 MB
    size_t required = (size_t)(mix_addr + (size_t)EE * 256 * sizeof(__half)
                               - (uintptr_t)d_ws);

    if (ws_size >= required) {
        // ---- materialized-mix (edge order) + high-occupancy atomic scatter ----
        hipMemsetAsync(agg, 0, (size_t)NN * 512 * sizeof(float), stream);
        up_kernel<<<NN / 16, 256, 0, stream>>>(node_feats, W_up_s, W_up_v, up, 1);
        mlp_kernel<<<EE / 256, 256, 0, stream>>>(radial,
            mlp_w1, mlp_w2, mlp_w3, mlp_wo, mix);
        scatter_kernel<<<2048, 256, 0, stream>>>(senders, receivers, vectors,
            mix, up, agg);
        node_kernel<<<NN / 16, 256, 0, stream>>>(node_feats, node_specie,
            W_down_s, W_down_v, W_skip_s, W_skip_v, agg, out);
    } else {
        // ---- fallback: round-3 fused atomic path ----
        hipMemsetAsync(agg, 0, (size_t)NN * 512 * sizeof(float), stream);
        up_kernel<<<NN / 16, 256, 0, stream>>>(node_feats, W_up_s, W_up_v, up, 0);
        edge_kernel_fb<<<EE / 256, 256, 0, stream>>>(
            vectors, radial, senders, receivers,
            mlp_w1, mlp_w2, mlp_w3, mlp_wo, up, agg);
        node_kernel<<<NN / 16, 256, 0, stream>>>(node_feats, node_specie,
            W_down_s, W_down_v, W_skip_s, W_skip_v, agg, out);
    }
}

// Round 8
// 1032.153 us; speedup vs baseline: 1.2674x; 1.2674x over previous
//
#include <hip/hip_runtime.h>
#include <hip/hip_fp16.h>

#define NN 20000
#define EE 320000

__device__ __forceinline__ float silu_f(float x) {
    return x / (1.0f + __expf(-x));
}

__device__ __forceinline__ unsigned pk_h2(float a, float b) {
    __half2 h = __floats2half2_rn(a, b);
    return *reinterpret_cast<unsigned*>(&h);
}

// ---------------- Kernel 1: node up-projection (16 nodes/block) ----------------
// dmajor=1: up2[n] = [ s(0..63) | evx(64..127) | evy(128..191) | evz(192..255) ]
// dmajor=0: legacy interleaved [ s(0..63) | ev[m][d] at 64+3m+d ]  (fallback path)
__global__ __launch_bounds__(256) void up_kernel(
    const float* __restrict__ nf, const float* __restrict__ Wus,
    const float* __restrict__ Wuv, float* __restrict__ up, int dmajor)
{
    __shared__ float sWs[64 * 64];
    __shared__ float sWv[64 * 64];
    int tid = threadIdx.x;
    for (int i = tid; i < 64 * 64; i += 256) { sWs[i] = Wus[i]; sWv[i] = Wuv[i]; }
    __syncthreads();
    int lane = tid & 63, wv = tid >> 6;
    for (int it = 0; it < 4; it++) {
        int n = blockIdx.x * 16 + wv * 4 + it;          // 1250*16 = 20000 exact
        const float* row = nf + (size_t)n * 256;
        float s  = row[lane];
        float v0 = row[64 + lane * 3 + 0];
        float v1 = row[64 + lane * 3 + 1];
        float v2 = row[64 + lane * 3 + 2];
        float as = 0.f, a0 = 0.f, a1 = 0.f, a2 = 0.f;
        #pragma unroll 8
        for (int m = 0; m < 64; m++) {
            float sm = __shfl(s, m);
            float b0 = __shfl(v0, m), b1 = __shfl(v1, m), b2 = __shfl(v2, m);
            float w_s = sWs[m * 64 + lane];
            float w_v = sWv[m * 64 + lane];
            as += sm * w_s;
            a0 += b0 * w_v; a1 += b1 * w_v; a2 += b2 * w_v;
        }
        float* o = up + (size_t)n * 256;
        if (dmajor) {
            o[lane]       = as * 0.125f;
            o[64  + lane] = a0 * 0.125f;
            o[128 + lane] = a1 * 0.125f;
            o[192 + lane] = a2 * 0.125f;
        } else {
            o[lane] = as * 0.125f;
            o[64 + lane * 3 + 0] = a0 * 0.125f;
            o[64 + lane * 3 + 1] = a1 * 0.125f;
            o[64 + lane * 3 + 2] = a2 * 0.125f;
        }
    }
}

// ---------------- Kernel 2: edge MLP -> mix (fp16, EDGE order) ----------------
// Thread-per-edge; fp16 hidden in thread-private LDS columns; zero barriers.
// LDS = 32 KiB -> 4 blocks/CU (16 waves/CU).
__global__ __launch_bounds__(256) void mlp_kernel(
    const float* __restrict__ radial,
    const float* __restrict__ w1, const float* __restrict__ w2,
    const float* __restrict__ w3, const float* __restrict__ wo,
    __half* __restrict__ mix)
{
    __shared__ __half2 hL[32 * 256];   // 32 KiB, thread-private columns

    int tid = threadIdx.x;
    int e = blockIdx.x * 256 + tid;    // 1250*256 = EE exact
    float4 ra = *(const float4*)(radial + (size_t)e * 8);
    float4 rb = *(const float4*)(radial + (size_t)e * 8 + 4);

    // layer 1: 8 -> 64
    {
        float a[64];
        #pragma unroll
        for (int j = 0; j < 64; j++) {
            float acc = ra.x * w1[j]       + ra.y * w1[64 + j]
                      + ra.z * w1[128 + j] + ra.w * w1[192 + j]
                      + rb.x * w1[256 + j] + rb.y * w1[320 + j]
                      + rb.z * w1[384 + j] + rb.w * w1[448 + j];
            a[j] = silu_f(acc * 0.35355339059327373f);
        }
        #pragma unroll
        for (int jp = 0; jp < 32; jp++)
            hL[jp * 256 + tid] = __floats2half2_rn(a[2 * jp], a[2 * jp + 1]);
    }
    // layer 2: 64 -> 64
    {
        float acc[64];
        #pragma unroll
        for (int j = 0; j < 64; j++) acc[j] = 0.f;
        #pragma unroll 4
        for (int kp = 0; kp < 32; kp++) {
            float2 hf = __half22float2(hL[kp * 256 + tid]);
            const float* wr0 = w2 + (size_t)(2 * kp) * 64;
            const float* wr1 = w2 + (size_t)(2 * kp + 1) * 64;
            #pragma unroll
            for (int j = 0; j < 64; j++) acc[j] += hf.x * wr0[j] + hf.y * wr1[j];
        }
        #pragma unroll
        for (int jp = 0; jp < 32; jp++)
            hL[jp * 256 + tid] = __floats2half2_rn(silu_f(acc[2 * jp] * 0.125f),
                                                   silu_f(acc[2 * jp + 1] * 0.125f));
    }
    // layer 3: 64 -> 64
    {
        float acc[64];
        #pragma unroll
        for (int j = 0; j < 64; j++) acc[j] = 0.f;
        #pragma unroll 4
        for (int kp = 0; kp < 32; kp++) {
            float2 hf = __half22float2(hL[kp * 256 + tid]);
            const float* wr0 = w3 + (size_t)(2 * kp) * 64;
            const float* wr1 = w3 + (size_t)(2 * kp + 1) * 64;
            #pragma unroll
            for (int j = 0; j < 64; j++) acc[j] += hf.x * wr0[j] + hf.y * wr1[j];
        }
        #pragma unroll
        for (int jp = 0; jp < 32; jp++)
            hL[jp * 256 + tid] = __floats2half2_rn(silu_f(acc[2 * jp] * 0.125f),
                                                   silu_f(acc[2 * jp + 1] * 0.125f));
    }

    // output layer: 64 -> 256 in 16 chunks of 16; direct packed stores
    for (int c = 0; c < 16; c++) {
        float ao[16];
        #pragma unroll
        for (int j = 0; j < 16; j++) ao[j] = 0.f;
        #pragma unroll 4
        for (int kp = 0; kp < 32; kp++) {
            float2 hf = __half22float2(hL[kp * 256 + tid]);
            const float* wr0 = wo + (size_t)(2 * kp) * 256 + c * 16;
            const float* wr1 = wo + (size_t)(2 * kp + 1) * 256 + c * 16;
            #pragma unroll
            for (int j = 0; j < 16; j++)
                ao[j] += hf.x * wr0[j] + hf.y * wr1[j];
        }
        #pragma unroll
        for (int j = 0; j < 16; j++) ao[j] *= 0.125f;
        uint4* dst = reinterpret_cast<uint4*>(mix + (size_t)e * 256 + c * 16);
        dst[0] = make_uint4(pk_h2(ao[0], ao[1]),  pk_h2(ao[2], ao[3]),
                            pk_h2(ao[4], ao[5]),  pk_h2(ao[6], ao[7]));
        dst[1] = make_uint4(pk_h2(ao[8], ao[9]),  pk_h2(ao[10], ao[11]),
                            pk_h2(ao[12], ao[13]), pk_h2(ao[14], ao[15]));
    }
}

// ---------------- Kernel 3: wave-per-edge scatter with packed-fp16 atomics ----------------
// agg is fp16 (row = 256 half2 = 512 feats). Per edge: 4 pk-atomic wave-instrs,
// each a contiguous 256B span. Halves the atomic dword count and HBM write-through
// vs f32 atomics. Lanes 0-31 handle even sections, 32-63 odd sections.
__global__ __launch_bounds__(256) void scatter_kernel(
    const int* __restrict__ senders, const int* __restrict__ receivers,
    const float* __restrict__ vectors, const __half* __restrict__ mix,
    const float* __restrict__ up2, __half2* __restrict__ agg)
{
    int lane = threadIdx.x & 63;
    int wid  = (blockIdx.x * 256 + threadIdx.x) >> 6;   // global wave id
    int nw   = gridDim.x * 4;
    const float SQ3 = 1.7320508075688772f;
    int i  = lane & 31;          // half2 index within a 64-feat section
    int i2 = i * 2;              // feature index
    bool lo = (lane < 32);

    for (int e = wid; e < EE; e += nw) {
        int snd = senders[e];
        int rcv = receivers[e];
        if ((unsigned)snd >= (unsigned)NN) snd = 0;
        if ((unsigned)rcv >= (unsigned)NN) rcv = 0;
        float vx = vectors[(size_t)e * 3 + 0];
        float vy = vectors[(size_t)e * 3 + 1];
        float vz = vectors[(size_t)e * 3 + 2];
        float l2 = vx * vx + vy * vy + vz * vz;
        float il   = (l2 > 0.f) ? rsqrtf(l2) : 0.f;
        float mask = (l2 > 0.f) ? 1.f : 0.f;

        const __half2* mr2 = (const __half2*)(mix + (size_t)e * 256);
        float2 mA = __half22float2(mr2[i]);
        float2 mB = __half22float2(mr2[32 + i]);
        float2 mC = __half22float2(mr2[64 + i]);
        float2 mD = __half22float2(mr2[96 + i]);
        float mA0 = mA.x * mask, mA1 = mA.y * mask;
        float mB0 = mB.x * mask, mB1 = mB.y * mask;
        float mC0 = mC.x * mask, mC1 = mC.y * mask;
        float mD0 = mD.x * mask, mD1 = mD.y * mask;

        const float* u = up2 + (size_t)snd * 256;
        float2 s2  = *(const float2*)(u + i2);
        float2 ex2 = *(const float2*)(u + 64  + i2);
        float2 ey2 = *(const float2*)(u + 128 + i2);
        float2 ez2 = *(const float2*)(u + 192 + i2);

        float tps0 = (ex2.x * vx + ey2.x * vy + ez2.x * vz) * il;
        float tps1 = (ex2.y * vx + ey2.y * vy + ez2.y * vz) * il;
        float yx = SQ3 * vx * il, yy = SQ3 * vy * il, yz = SQ3 * vz * il;

        // t0: s | tps ; t1: Cx | Cy ; t2: Cz | Dx ; t3: Dy | Dz
        float v0x = lo ? s2.x * mA0 : tps0 * mB0;
        float v0y = lo ? s2.y * mA1 : tps1 * mB1;
        float v1x = lo ? ex2.x * mC0 : ey2.x * mC0;
        float v1y = lo ? ex2.y * mC1 : ey2.y * mC1;
        float v2x = lo ? ez2.x * mC0 : s2.x * yx * mD0;
        float v2y = lo ? ez2.y * mC1 : s2.y * yx * mD1;
        float v3x = lo ? s2.x * yy * mD0 : s2.x * yz * mD0;
        float v3y = lo ? s2.y * yy * mD1 : s2.y * yz * mD1;

        __half2* ar = agg + (size_t)rcv * 256;
        unsafeAtomicAdd(ar + lane,       __floats2half2_rn(v0x, v0y));
        unsafeAtomicAdd(ar + 64  + lane, __floats2half2_rn(v1x, v1y));
        unsafeAtomicAdd(ar + 128 + lane, __floats2half2_rn(v2x, v2y));
        unsafeAtomicAdd(ar + 192 + lane, __floats2half2_rn(v3x, v3y));
    }
}

// ---------------- Kernel 4: node tail, fp16 agg (primary path) ----------------
__global__ __launch_bounds__(256) void node_kernel_h(
    const float* __restrict__ nf, const int* __restrict__ specie,
    const float* __restrict__ Wds, const float* __restrict__ Wdv,
    const float* __restrict__ Wss, const float* __restrict__ Wsv,
    const __half* __restrict__ agg, float* __restrict__ out)
{
    __shared__ float sDs[128 * 128];  // 64 KiB
    __shared__ float sDv[128 * 64];   // 32 KiB
    int tid = threadIdx.x;
    for (int i = tid; i < 128 * 128; i += 256) sDs[i] = Wds[i];
    for (int i = tid; i < 128 * 64; i += 256) sDv[i] = Wdv[i];
    __syncthreads();
    int lane = tid & 63, wv = tid >> 6;
    for (int it = 0; it < 4; it++) {
        int n = blockIdx.x * 16 + wv * 4 + it;
        const __half* arow = agg + (size_t)n * 512;
        const float inv_nei = 0.25f;
        float as0 = __half2float(arow[lane]) * inv_nei;
        float as1 = __half2float(arow[64 + lane]) * inv_nei;
        float av00 = __half2float(arow[128 + lane]) * inv_nei;
        float av01 = __half2float(arow[192 + lane]) * inv_nei;
        float av02 = __half2float(arow[256 + lane]) * inv_nei;
        float av10 = __half2float(arow[320 + lane]) * inv_nei;
        float av11 = __half2float(arow[384 + lane]) * inv_nei;
        float av12 = __half2float(arow[448 + lane]) * inv_nei;
        const float* row = nf + (size_t)n * 256;
        float s   = row[lane];
        float vv0 = row[64 + lane * 3 + 0];
        float vv1 = row[64 + lane * 3 + 1];
        float vv2 = row[64 + lane * 3 + 2];

        float f0 = 0.f, f1 = 0.f, fv0 = 0.f, fv1 = 0.f, fv2 = 0.f;
        #pragma unroll 8
        for (int m = 0; m < 64; m++) {
            float am = __shfl(as0, m);
            f0 += am * sDs[m * 128 + lane];
            f1 += am * sDs[m * 128 + 64 + lane];
            float b0 = __shfl(av00, m), b1 = __shfl(av01, m), b2 = __shfl(av02, m);
            float wd = sDv[m * 64 + lane];
            fv0 += b0 * wd; fv1 += b1 * wd; fv2 += b2 * wd;
        }
        #pragma unroll 8
        for (int m = 0; m < 64; m++) {
            float am = __shfl(as1, m);
            f0 += am * sDs[(64 + m) * 128 + lane];
            f1 += am * sDs[(64 + m) * 128 + 64 + lane];
            float b0 = __shfl(av10, m), b1 = __shfl(av11, m), b2 = __shfl(av12, m);
            float wd = sDv[(64 + m) * 64 + lane];
            fv0 += b0 * wd; fv1 += b1 * wd; fv2 += b2 * wd;
        }
        const float inv2m = 0.08838834764831845f;
        f0 *= inv2m; f1 *= inv2m; fv0 *= inv2m; fv1 *= inv2m; fv2 *= inv2m;

        int sp = specie[n];
        if ((unsigned)sp >= 5u) sp = 0;
        const float* Ws = Wss + (size_t)sp * 64 * 128;
        const float* Wv = Wsv + (size_t)sp * 64 * 64;
        float g0 = 0.f, g1 = 0.f, h0 = 0.f, h1 = 0.f, h2 = 0.f;
        #pragma unroll 4
        for (int m = 0; m < 64; m++) {
            float sm = __shfl(s, m);
            g0 += sm * Ws[m * 128 + lane];
            g1 += sm * Ws[m * 128 + 64 + lane];
            float b0 = __shfl(vv0, m), b1 = __shfl(vv1, m), b2 = __shfl(vv2, m);
            float wsk = Wv[m * 64 + lane];
            h0 += b0 * wsk; h1 += b1 * wsk; h2 += b2 * wsk;
        }
        f0 += g0 * 0.125f; f1 += g1 * 0.125f;
        fv0 += h0 * 0.125f; fv1 += h1 * 0.125f; fv2 += h2 * 0.125f;

        float gs   = silu_f(f0);
        float gate = silu_f(f1);
        float* orow = out + (size_t)n * 256;
        orow[lane] = fmaxf(gs, 0.f);
        orow[64 + lane * 3 + 0] = fmaxf(gate * fv0, 0.f);
        orow[64 + lane * 3 + 1] = fmaxf(gate * fv1, 0.f);
        orow[64 + lane * 3 + 2] = fmaxf(gate * fv2, 0.f);
    }
}

// ---------------- Kernel 4b: node tail, f32 agg (fallback path) ----------------
__global__ __launch_bounds__(256) void node_kernel_f(
    const float* __restrict__ nf, const int* __restrict__ specie,
    const float* __restrict__ Wds, const float* __restrict__ Wdv,
    const float* __restrict__ Wss, const float* __restrict__ Wsv,
    const float* __restrict__ agg, float* __restrict__ out)
{
    __shared__ float sDs[128 * 128];
    __shared__ float sDv[128 * 64];
    int tid = threadIdx.x;
    for (int i = tid; i < 128 * 128; i += 256) sDs[i] = Wds[i];
    for (int i = tid; i < 128 * 64; i += 256) sDv[i] = Wdv[i];
    __syncthreads();
    int lane = tid & 63, wv = tid >> 6;
    for (int it = 0; it < 4; it++) {
        int n = blockIdx.x * 16 + wv * 4 + it;
        const float* arow = agg + (size_t)n * 512;
        const float inv_nei = 0.25f;
        float as0 = arow[lane] * inv_nei;
        float as1 = arow[64 + lane] * inv_nei;
        float av00 = arow[128 + lane] * inv_nei;
        float av01 = arow[192 + lane] * inv_nei;
        float av02 = arow[256 + lane] * inv_nei;
        float av10 = arow[320 + lane] * inv_nei;
        float av11 = arow[384 + lane] * inv_nei;
        float av12 = arow[448 + lane] * inv_nei;
        const float* row = nf + (size_t)n * 256;
        float s   = row[lane];
        float vv0 = row[64 + lane * 3 + 0];
        float vv1 = row[64 + lane * 3 + 1];
        float vv2 = row[64 + lane * 3 + 2];

        float f0 = 0.f, f1 = 0.f, fv0 = 0.f, fv1 = 0.f, fv2 = 0.f;
        #pragma unroll 8
        for (int m = 0; m < 64; m++) {
            float am = __shfl(as0, m);
            f0 += am * sDs[m * 128 + lane];
            f1 += am * sDs[m * 128 + 64 + lane];
            float b0 = __shfl(av00, m), b1 = __shfl(av01, m), b2 = __shfl(av02, m);
            float wd = sDv[m * 64 + lane];
            fv0 += b0 * wd; fv1 += b1 * wd; fv2 += b2 * wd;
        }
        #pragma unroll 8
        for (int m = 0; m < 64; m++) {
            float am = __shfl(as1, m);
            f0 += am * sDs[(64 + m) * 128 + lane];
            f1 += am * sDs[(64 + m) * 128 + 64 + lane];
            float b0 = __shfl(av10, m), b1 = __shfl(av11, m), b2 = __shfl(av12, m);
            float wd = sDv[(64 + m) * 64 + lane];
            fv0 += b0 * wd; fv1 += b1 * wd; fv2 += b2 * wd;
        }
        const float inv2m = 0.08838834764831845f;
        f0 *= inv2m; f1 *= inv2m; fv0 *= inv2m; fv1 *= inv2m; fv2 *= inv2m;

        int sp = specie[n];
        if ((unsigned)sp >= 5u) sp = 0;
        const float* Ws = Wss + (size_t)sp * 64 * 128;
        const float* Wv = Wsv + (size_t)sp * 64 * 64;
        float g0 = 0.f, g1 = 0.f, h0 = 0.f, h1 = 0.f, h2 = 0.f;
        #pragma unroll 4
        for (int m = 0; m < 64; m++) {
            float sm = __shfl(s, m);
            g0 += sm * Ws[m * 128 + lane];
            g1 += sm * Ws[m * 128 + 64 + lane];
            float b0 = __shfl(vv0, m), b1 = __shfl(vv1, m), b2 = __shfl(vv2, m);
            float wsk = Wv[m * 64 + lane];
            h0 += b0 * wsk; h1 += b1 * wsk; h2 += b2 * wsk;
        }
        f0 += g0 * 0.125f; f1 += g1 * 0.125f;
        fv0 += h0 * 0.125f; fv1 += h1 * 0.125f; fv2 += h2 * 0.125f;

        float gs   = silu_f(f0);
        float gate = silu_f(f1);
        float* orow = out + (size_t)n * 256;
        orow[lane] = fmaxf(gs, 0.f);
        orow[64 + lane * 3 + 0] = fmaxf(gate * fv0, 0.f);
        orow[64 + lane * 3 + 1] = fmaxf(gate * fv1, 0.f);
        orow[64 + lane * 3 + 2] = fmaxf(gate * fv2, 0.f);
    }
}

// ---------------- Fallback: round-3 fused edge kernel (interleaved up layout) ----------------
__global__ __launch_bounds__(256) void edge_kernel_fb(
    const float* __restrict__ vectors, const float* __restrict__ radial,
    const int* __restrict__ senders, const int* __restrict__ receivers,
    const float* __restrict__ w1, const float* __restrict__ w2,
    const float* __restrict__ w3, const float* __restrict__ wo,
    const float* __restrict__ up, float* __restrict__ agg)
{
    __shared__ __half2 hL[32 * 256];
    __shared__ float   T[16 * 256];
    __shared__ float   sVec[256 * 3];
    __shared__ int     sSnd[256];
    __shared__ int     sRcv[256];

    int tid = threadIdx.x;
    int e = blockIdx.x * 256 + tid;
    int snd = senders[e];
    int rcv = receivers[e];
    if ((unsigned)snd >= (unsigned)NN) snd = 0;
    if ((unsigned)rcv >= (unsigned)NN) rcv = 0;
    float4 ra = *(const float4*)(radial + (size_t)e * 8);
    float4 rb = *(const float4*)(radial + (size_t)e * 8 + 4);
    float vx = vectors[(size_t)e * 3 + 0];
    float vy = vectors[(size_t)e * 3 + 1];
    float vz = vectors[(size_t)e * 3 + 2];
    sSnd[tid] = snd; sRcv[tid] = rcv;
    sVec[tid * 3 + 0] = vx; sVec[tid * 3 + 1] = vy; sVec[tid * 3 + 2] = vz;
    float len2 = vx * vx + vy * vy + vz * vz;
    float mask = (len2 > 0.f) ? 1.f : 0.f;

    {
        float a[64];
        #pragma unroll
        for (int j = 0; j < 64; j++) {
            float acc = ra.x * w1[j]       + ra.y * w1[64 + j]
                      + ra.z * w1[128 + j] + ra.w * w1[192 + j]
                      + rb.x * w1[256 + j] + rb.y * w1[320 + j]
                      + rb.z * w1[384 + j] + rb.w * w1[448 + j];
            a[j] = silu_f(acc * 0.35355339059327373f);
        }
        #pragma unroll
        for (int jp = 0; jp < 32; jp++)
            hL[jp * 256 + tid] = __floats2half2_rn(a[2 * jp], a[2 * jp + 1]);
    }
    {
        float acc[64];
        #pragma unroll
        for (int j = 0; j < 64; j++) acc[j] = 0.f;
        #pragma unroll 2
        for (int kp = 0; kp < 32; kp++) {
            float2 hf = __half22float2(hL[kp * 256 + tid]);
            const float* wr0 = w2 + (size_t)(2 * kp) * 64;
            const float* wr1 = w2 + (size_t)(2 * kp + 1) * 64;
            #pragma unroll
            for (int j = 0; j < 64; j++) acc[j] += hf.x * wr0[j] + hf.y * wr1[j];
        }
        #pragma unroll
        for (int jp = 0; jp < 32; jp++)
            hL[jp * 256 + tid] = __floats2half2_rn(silu_f(acc[2 * jp] * 0.125f),
                                                   silu_f(acc[2 * jp + 1] * 0.125f));
    }
    {
        float acc[64];
        #pragma unroll
        for (int j = 0; j < 64; j++) acc[j] = 0.f;
        #pragma unroll 2
        for (int kp = 0; kp < 32; kp++) {
            float2 hf = __half22float2(hL[kp * 256 + tid]);
            const float* wr0 = w3 + (size_t)(2 * kp) * 64;
            const float* wr1 = w3 + (size_t)(2 * kp + 1) * 64;
            #pragma unroll
            for (int j = 0; j < 64; j++) acc[j] += hf.x * wr0[j] + hf.y * wr1[j];
        }
        #pragma unroll
        for (int jp = 0; jp < 32; jp++)
            hL[jp * 256 + tid] = __floats2half2_rn(silu_f(acc[2 * jp] * 0.125f),
                                                   silu_f(acc[2 * jp + 1] * 0.125f));
    }

    int lane  = tid & 63;
    int wbase = tid & 192;
    int f = lane & 15;
    int g = lane >> 4;

    #define COMPUTE_CHUNK(c, ao)                                                \
        {                                                                       \
            _Pragma("unroll")                                                   \
            for (int j = 0; j < 16; j++) ao[j] = 0.f;                           \
            _Pragma("unroll 4")                                                 \
            for (int kp = 0; kp < 32; kp++) {                                   \
                float2 hf = __half22float2(hL[kp * 256 + tid]);                 \
                const float* wr0 = wo + (size_t)(2 * kp) * 256 + (c) * 16;      \
                const float* wr1 = wo + (size_t)(2 * kp + 1) * 256 + (c) * 16;  \
                _Pragma("unroll")                                               \
                for (int j = 0; j < 16; j++)                                    \
                    ao[j] += hf.x * wr0[j] + hf.y * wr1[j];                     \
            }                                                                   \
            _Pragma("unroll")                                                   \
            for (int j = 0; j < 16; j++) ao[j] *= 0.125f * mask;                \
        }

    #define WRITE_T(ao)                                                         \
        __syncthreads();                                                        \
        _Pragma("unroll")                                                       \
        for (int j = 0; j < 16; j++) T[j * 256 + (tid ^ (2 * j))] = ao[j];      \
        __syncthreads();

    for (int c = 0; c < 4; c++) {
        float ao[16];
        COMPUTE_CHUNK(c, ao)
        WRITE_T(ao)
        for (int el = 0; el < 16; el++) {
            int col = wbase + el * 4 + g;
            int s_ = sSnd[col], rc = sRcv[col];
            float mx = T[f * 256 + (col ^ (2 * f))];
            int jf = c * 16 + f;
            atomicAdd(agg + (size_t)rc * 512 + jf, up[(size_t)s_ * 256 + jf] * mx);
        }
    }
    for (int c = 4; c < 8; c++) {
        float ao[16];
        COMPUTE_CHUNK(c, ao)
        WRITE_T(ao)
        for (int el = 0; el < 16; el++) {
            int col = wbase + el * 4 + g;
            int s_ = sSnd[col], rc = sRcv[col];
            float wx = sVec[col * 3 + 0], wy = sVec[col * 3 + 1], wz = sVec[col * 3 + 2];
            float l2 = wx * wx + wy * wy + wz * wz;
            float il = (l2 > 0.f) ? rsqrtf(l2) : 0.f;
            float mx = T[f * 256 + (col ^ (2 * f))];
            int m = (c - 4) * 16 + f;
            const float* ev = up + (size_t)s_ * 256 + 64 + m * 3;
            float dot = ev[0] * wx + ev[1] * wy + ev[2] * wz;
            atomicAdd(agg + (size_t)rc * 512 + 64 + m, dot * il * mx);
        }
    }
    for (int c = 8; c < 12; c++) {
        float ao[16];
        COMPUTE_CHUNK(c, ao)
        WRITE_T(ao)
        for (int el = 0; el < 16; el++) {
            int col = wbase + el * 4 + g;
            int s_ = sSnd[col], rc = sRcv[col];
            float mx = T[f * 256 + (col ^ (2 * f))];
            int m = (c - 8) * 16 + f;
            const float* ev = up + (size_t)s_ * 256 + 64 + m * 3;
            float* ag = agg + (size_t)rc * 512 + 128 + m;
            atomicAdd(ag + 0,   ev[0] * mx);
            atomicAdd(ag + 64,  ev[1] * mx);
            atomicAdd(ag + 128, ev[2] * mx);
        }
    }
    for (int c = 12; c < 16; c++) {
        float ao[16];
        COMPUTE_CHUNK(c, ao)
        WRITE_T(ao)
        for (int el = 0; el < 16; el++) {
            int col = wbase + el * 4 + g;
            int s_ = sSnd[col], rc = sRcv[col];
            float wx = sVec[col * 3 + 0], wy = sVec[col * 3 + 1], wz = sVec[col * 3 + 2];
            float l2 = wx * wx + wy * wy + wz * wz;
            float il = (l2 > 0.f) ? rsqrtf(l2) : 0.f;
            float mx = T[f * 256 + (col ^ (2 * f))];
            int m = (c - 12) * 16 + f;
            float sc = up[(size_t)s_ * 256 + m] * 1.7320508075688772f * il * mx;
            float* ag = agg + (size_t)rc * 512 + 320 + m;
            atomicAdd(ag + 0,   sc * wx);
            atomicAdd(ag + 64,  sc * wy);
            atomicAdd(ag + 128, sc * wz);
        }
    }
    #undef COMPUTE_CHUNK
    #undef WRITE_T
}

extern "C" void kernel_launch(void* const* d_in, const int* in_sizes, int n_in,
                              void* d_out, int out_size, void* d_ws, size_t ws_size,
                              hipStream_t stream) {
    const float* vectors     = (const float*)d_in[0];
    const float* node_feats  = (const float*)d_in[1];
    const int*   node_specie = (const int*)d_in[2];
    const float* radial      = (const float*)d_in[3];
    const int*   senders     = (const int*)d_in[4];
    const int*   receivers   = (const int*)d_in[5];
    const float* W_up_s      = (const float*)d_in[6];
    const float* W_up_v      = (const float*)d_in[7];
    const float* mlp_w1      = (const float*)d_in[8];
    const float* mlp_w2      = (const float*)d_in[9];
    const float* mlp_w3      = (const float*)d_in[10];
    const float* mlp_w4      = (const float*)d_in[11];
    const float* W_skip_s    = (const float*)d_in[12];
    const float* W_skip_v    = (const float*)d_in[13];
    const float* W_down_s    = (const float*)d_in[14];
    const float* W_down_v    = (const float*)d_in[15];
    float* out = (float*)d_out;

    // workspace layout: up | agg-region (f32-sized, reused) | mix (256B-aligned)
    float* up   = (float*)d_ws;                      // NN*256 f32  = 20.48 MB
    float* aggf = up + (size_t)NN * 256;             // NN*512 f32  = 40.96 MB (fallback)
    __half2* aggh = (__half2*)aggf;                  // NN*256 half2 = 20.48 MB (primary)
    uintptr_t mix_addr = ((uintptr_t)(aggf + (size_t)NN * 512) + 255) & ~(uintptr_t)255;
    __half* mix = (__half*)mix_addr;                 // EE*256 fp16 = 163.84 MB
    size_t required = (size_t)(mix_addr + (size_t)EE * 256 * sizeof(__half)
                               - (uintptr_t)d_ws);

    if (ws_size >= required) {
        // ---- materialized-mix + packed-fp16 atomic scatter ----
        hipMemsetAsync(aggh, 0, (size_t)NN * 512 * sizeof(__half), stream);
        up_kernel<<<NN / 16, 256, 0, stream>>>(node_feats, W_up_s, W_up_v, up, 1);
        mlp_kernel<<<EE / 256, 256, 0, stream>>>(radial,
            mlp_w1, mlp_w2, mlp_w3, mlp_w4, mix);
        scatter_kernel<<<2048, 256, 0, stream>>>(senders, receivers, vectors,
            mix, up, aggh);
        node_kernel_h<<<NN / 16, 256, 0, stream>>>(node_feats, node_specie,
            W_down_s, W_down_v, W_skip_s, W_skip_v, (const __half*)aggh, out);
    } else {
        // ---- fallback: round-3 fused atomic path (f32 agg) ----
        hipMemsetAsync(aggf, 0, (size_t)NN * 512 * sizeof(float), stream);
        up_kernel<<<NN / 16, 256, 0, stream>>>(node_feats, W_up_s, W_up_v, up, 0);
        edge_kernel_fb<<<EE / 256, 256, 0, stream>>>(
            vectors, radial, senders, receivers,
            mlp_w1, mlp_w2, mlp_w3, mlp_w4, up, aggf);
        node_kernel_f<<<NN / 16, 256, 0, stream>>>(node_feats, node_specie,
            W_down_s, W_down_v, W_skip_s, W_skip_v, aggf, out);
    }
}

// Round 9
// 636.921 us; speedup vs baseline: 2.0539x; 1.6205x over previous
//
#include <hip/hip_runtime.h>
#include <hip/hip_fp16.h>

#define NN 20000
#define EE 320000

typedef _Float16 f16;
typedef f16  f16x8 __attribute__((ext_vector_type(8)));
typedef float f32x4 __attribute__((ext_vector_type(4)));

__device__ __forceinline__ float silu_f(float x) {
    return x / (1.0f + __expf(-x));
}

// ---------------- Kernel 1: node up-projection (16 nodes/block) ----------------
__global__ __launch_bounds__(256) void up_kernel(
    const float* __restrict__ nf, const float* __restrict__ Wus,
    const float* __restrict__ Wuv, float* __restrict__ up, int dmajor)
{
    __shared__ float sWs[64 * 64];
    __shared__ float sWv[64 * 64];
    int tid = threadIdx.x;
    for (int i = tid; i < 64 * 64; i += 256) { sWs[i] = Wus[i]; sWv[i] = Wuv[i]; }
    __syncthreads();
    int lane = tid & 63, wv = tid >> 6;
    for (int it = 0; it < 4; it++) {
        int n = blockIdx.x * 16 + wv * 4 + it;
        const float* row = nf + (size_t)n * 256;
        float s  = row[lane];
        float v0 = row[64 + lane * 3 + 0];
        float v1 = row[64 + lane * 3 + 1];
        float v2 = row[64 + lane * 3 + 2];
        float as = 0.f, a0 = 0.f, a1 = 0.f, a2 = 0.f;
        #pragma unroll 8
        for (int m = 0; m < 64; m++) {
            float sm = __shfl(s, m);
            float b0 = __shfl(v0, m), b1 = __shfl(v1, m), b2 = __shfl(v2, m);
            float w_s = sWs[m * 64 + lane];
            float w_v = sWv[m * 64 + lane];
            as += sm * w_s;
            a0 += b0 * w_v; a1 += b1 * w_v; a2 += b2 * w_v;
        }
        float* o = up + (size_t)n * 256;
        if (dmajor) {
            o[lane]       = as * 0.125f;
            o[64  + lane] = a0 * 0.125f;
            o[128 + lane] = a1 * 0.125f;
            o[192 + lane] = a2 * 0.125f;
        } else {
            o[lane] = as * 0.125f;
            o[64 + lane * 3 + 0] = a0 * 0.125f;
            o[64 + lane * 3 + 1] = a1 * 0.125f;
            o[64 + lane * 3 + 2] = a2 * 0.125f;
        }
    }
}

// ---------------- Weight packing into MFMA B-fragment order ----------------
// Fragment layout (v_mfma_f32_16x16x32_f16 B operand): lane l supplies
// B[k][col] with col = l&15, k = 8*(l>>4)+i (i=0..7), khalf h adds +32.
// frag ids: 0-3 L1(t) | 4-11 L2(t,h) | 12-19 L3(t,h) | 20-51 OUT(t,h)
__global__ __launch_bounds__(256) void pack_kernel(
    const float* __restrict__ w1, const float* __restrict__ w2,
    const float* __restrict__ w3, const float* __restrict__ wo,
    f16* __restrict__ wp)
{
    int idx = blockIdx.x * 256 + threadIdx.x;   // 13*256 = 3328 = 52*64
    if (idx >= 52 * 64) return;
    int frag = idx >> 6, lane = idx & 63;
    int col = lane & 15, kg = lane >> 4;
    f16x8 pv;
    if (frag < 4) {
        int t = frag;
        #pragma unroll
        for (int i = 0; i < 8; i++) {
            int k = kg * 8 + i;
            pv[i] = (k < 8) ? (f16)w1[k * 64 + t * 16 + col] : (f16)0.f;
        }
    } else if (frag < 12) {
        int f = frag - 4, t = f >> 1, h = f & 1;
        #pragma unroll
        for (int i = 0; i < 8; i++) {
            int k = h * 32 + kg * 8 + i;
            pv[i] = (f16)w2[k * 64 + t * 16 + col];
        }
    } else if (frag < 20) {
        int f = frag - 12, t = f >> 1, h = f & 1;
        #pragma unroll
        for (int i = 0; i < 8; i++) {
            int k = h * 32 + kg * 8 + i;
            pv[i] = (f16)w3[k * 64 + t * 16 + col];
        }
    } else {
        int f = frag - 20, t = f >> 1, h = f & 1;
        #pragma unroll
        for (int i = 0; i < 8; i++) {
            int k = h * 32 + kg * 8 + i;
            pv[i] = (f16)wo[k * 256 + t * 16 + col];
        }
    }
    *(f16x8*)(wp + (size_t)idx * 8) = pv;
}

// ---------------- Kernel 2: MFMA edge MLP -> mix ----------------
// Wave = 16 edges. Layers via 16x16x32 f16 MFMA. Activations in per-wave
// XOR-swizzled LDS ping-pong (<=2-way banks, free). mix written through an
// 8KB staging tile -> 1KB-contiguous coalesced stores.
__global__ __launch_bounds__(256) void mlp_mfma(
    const float* __restrict__ radial, const f16* __restrict__ wp,
    f16* __restrict__ mix)
{
    __shared__ f16 smem[4 * 6144];   // 48 KiB: per wave actA(1024)|actB(1024)|outT(4096)
    int tid = threadIdx.x, lane = tid & 63, w = tid >> 6;
    f16* actA = smem + w * 6144;
    f16* actB = actA + 1024;
    f16* outT = actB + 1024;
    int e0 = (blockIdx.x * 4 + w) * 16;

    int col = lane & 15;
    int kg  = lane >> 4;
    const f32x4 zero = {0.f, 0.f, 0.f, 0.f};

    // B fragment load (global, coalesced 16B/lane, L2-resident)
    #define LDB(fr) (*(const f16x8*)(wp + ((size_t)(fr) * 64 + lane) * 8))
    // A fragment load from swizzled act buffer: row=lane&15, k=8*kg+32h
    #define LDA(buf, h) (*(const f16x8*)((buf) + (lane & 15) * 64 + \
                        (((kg * 8) + (h) * 32) ^ (((lane & 15) & 7) << 3))))
    // store D tile (acc[t][r] at row=4*kg+r, col=t*16+col) with silu+scale
    #define STACT(buf, acc, SC)                                            \
        _Pragma("unroll")                                                  \
        for (int t = 0; t < 4; t++) {                                      \
            _Pragma("unroll")                                              \
            for (int r = 0; r < 4; r++) {                                  \
                int row = kg * 4 + r;                                      \
                int c   = t * 16 + col;                                    \
                float x = acc[t][r] * (SC);                                \
                (buf)[row * 64 + (c ^ ((row & 7) << 3))] = (f16)silu_f(x); \
            }                                                              \
        }

    // ---- layer 1: 8 -> 64 (K zero-padded to 32) ----
    {
        f16x8 a;
        if (lane < 16) {
            const float* rr = radial + (size_t)(e0 + lane) * 8;
            float4 ra = *(const float4*)rr;
            float4 rb = *(const float4*)(rr + 4);
            a[0] = (f16)ra.x; a[1] = (f16)ra.y; a[2] = (f16)ra.z; a[3] = (f16)ra.w;
            a[4] = (f16)rb.x; a[5] = (f16)rb.y; a[6] = (f16)rb.z; a[7] = (f16)rb.w;
        } else {
            #pragma unroll
            for (int i = 0; i < 8; i++) a[i] = (f16)0.f;
        }
        f32x4 acc[4];
        #pragma unroll
        for (int t = 0; t < 4; t++)
            acc[t] = __builtin_amdgcn_mfma_f32_16x16x32_f16(a, LDB(t), zero, 0, 0, 0);
        STACT(actA, acc, 0.35355339059327373f)
    }
    // ---- layer 2: 64 -> 64 (actA -> actB) ----
    {
        f16x8 a0 = LDA(actA, 0), a1 = LDA(actA, 1);
        f32x4 acc[4];
        #pragma unroll
        for (int t = 0; t < 4; t++) {
            acc[t] = __builtin_amdgcn_mfma_f32_16x16x32_f16(a0, LDB(4 + t * 2), zero, 0, 0, 0);
            acc[t] = __builtin_amdgcn_mfma_f32_16x16x32_f16(a1, LDB(5 + t * 2), acc[t], 0, 0, 0);
        }
        STACT(actB, acc, 0.125f)
    }
    // ---- layer 3: 64 -> 64 (actB -> actA) ----
    {
        f16x8 a0 = LDA(actB, 0), a1 = LDA(actB, 1);
        f32x4 acc[4];
        #pragma unroll
        for (int t = 0; t < 4; t++) {
            acc[t] = __builtin_amdgcn_mfma_f32_16x16x32_f16(a0, LDB(12 + t * 2), zero, 0, 0, 0);
            acc[t] = __builtin_amdgcn_mfma_f32_16x16x32_f16(a1, LDB(13 + t * 2), acc[t], 0, 0, 0);
        }
        STACT(actA, acc, 0.125f)
    }
    // ---- output layer: 64 -> 256 (actA -> outT), 4 groups of 4 tiles ----
    {
        f16x8 a0 = LDA(actA, 0), a1 = LDA(actA, 1);
        #pragma unroll
        for (int tg = 0; tg < 4; tg++) {
            f32x4 acc[4];
            #pragma unroll
            for (int q = 0; q < 4; q++) {
                int t = tg * 4 + q;
                acc[q] = __builtin_amdgcn_mfma_f32_16x16x32_f16(a0, LDB(20 + t * 2), zero, 0, 0, 0);
                acc[q] = __builtin_amdgcn_mfma_f32_16x16x32_f16(a1, LDB(21 + t * 2), acc[q], 0, 0, 0);
            }
            #pragma unroll
            for (int q = 0; q < 4; q++) {
                int t = tg * 4 + q;
                #pragma unroll
                for (int r = 0; r < 4; r++) {
                    int row = kg * 4 + r;
                    int c   = t * 16 + col;
                    outT[row * 256 + (c ^ ((row & 7) << 3))] = (f16)(acc[q][r] * 0.125f);
                }
            }
        }
    }
    // ---- coalesced store: 8 x 1KB contiguous ----
    #pragma unroll
    for (int j = 0; j < 8; j++) {
        int li  = j * 64 + lane;
        int row = li >> 5;
        int ci  = (li & 31) * 8;
        f16x8 v = *(const f16x8*)(outT + row * 256 + (ci ^ ((row & 7) << 3)));
        *(f16x8*)(mix + (size_t)(e0 + row) * 256 + ci) = v;
    }
    #undef LDB
    #undef LDA
    #undef STACT
}

// ---------------- Kernel 3: wave-per-edge scatter with packed-fp16 atomics ----------------
__global__ __launch_bounds__(256) void scatter_kernel(
    const int* __restrict__ senders, const int* __restrict__ receivers,
    const float* __restrict__ vectors, const __half* __restrict__ mix,
    const float* __restrict__ up2, __half2* __restrict__ agg)
{
    int lane = threadIdx.x & 63;
    int wid  = (blockIdx.x * 256 + threadIdx.x) >> 6;
    int nw   = gridDim.x * 4;
    const float SQ3 = 1.7320508075688772f;
    int i  = lane & 31;
    int i2 = i * 2;
    bool lo = (lane < 32);

    for (int e = wid; e < EE; e += nw) {
        int snd = senders[e];
        int rcv = receivers[e];
        if ((unsigned)snd >= (unsigned)NN) snd = 0;
        if ((unsigned)rcv >= (unsigned)NN) rcv = 0;
        float vx = vectors[(size_t)e * 3 + 0];
        float vy = vectors[(size_t)e * 3 + 1];
        float vz = vectors[(size_t)e * 3 + 2];
        float l2 = vx * vx + vy * vy + vz * vz;
        float il   = (l2 > 0.f) ? rsqrtf(l2) : 0.f;
        float mask = (l2 > 0.f) ? 1.f : 0.f;

        const __half2* mr2 = (const __half2*)(mix + (size_t)e * 256);
        float2 mA = __half22float2(mr2[i]);
        float2 mB = __half22float2(mr2[32 + i]);
        float2 mC = __half22float2(mr2[64 + i]);
        float2 mD = __half22float2(mr2[96 + i]);
        float mA0 = mA.x * mask, mA1 = mA.y * mask;
        float mB0 = mB.x * mask, mB1 = mB.y * mask;
        float mC0 = mC.x * mask, mC1 = mC.y * mask;
        float mD0 = mD.x * mask, mD1 = mD.y * mask;

        const float* u = up2 + (size_t)snd * 256;
        float2 s2  = *(const float2*)(u + i2);
        float2 ex2 = *(const float2*)(u + 64  + i2);
        float2 ey2 = *(const float2*)(u + 128 + i2);
        float2 ez2 = *(const float2*)(u + 192 + i2);

        float tps0 = (ex2.x * vx + ey2.x * vy + ez2.x * vz) * il;
        float tps1 = (ex2.y * vx + ey2.y * vy + ez2.y * vz) * il;
        float yx = SQ3 * vx * il, yy = SQ3 * vy * il, yz = SQ3 * vz * il;

        float v0x = lo ? s2.x * mA0 : tps0 * mB0;
        float v0y = lo ? s2.y * mA1 : tps1 * mB1;
        float v1x = lo ? ex2.x * mC0 : ey2.x * mC0;
        float v1y = lo ? ex2.y * mC1 : ey2.y * mC1;
        float v2x = lo ? ez2.x * mC0 : s2.x * yx * mD0;
        float v2y = lo ? ez2.y * mC1 : s2.y * yx * mD1;
        float v3x = lo ? s2.x * yy * mD0 : s2.x * yz * mD0;
        float v3y = lo ? s2.y * yy * mD1 : s2.y * yz * mD1;

        __half2* ar = agg + (size_t)rcv * 256;
        unsafeAtomicAdd(ar + lane,       __floats2half2_rn(v0x, v0y));
        unsafeAtomicAdd(ar + 64  + lane, __floats2half2_rn(v1x, v1y));
        unsafeAtomicAdd(ar + 128 + lane, __floats2half2_rn(v2x, v2y));
        unsafeAtomicAdd(ar + 192 + lane, __floats2half2_rn(v3x, v3y));
    }
}

// ---------------- Kernel 4: node tail, fp16 agg (primary path) ----------------
__global__ __launch_bounds__(256) void node_kernel_h(
    const float* __restrict__ nf, const int* __restrict__ specie,
    const float* __restrict__ Wds, const float* __restrict__ Wdv,
    const float* __restrict__ Wss, const float* __restrict__ Wsv,
    const __half* __restrict__ agg, float* __restrict__ out)
{
    __shared__ float sDs[128 * 128];
    __shared__ float sDv[128 * 64];
    int tid = threadIdx.x;
    for (int i = tid; i < 128 * 128; i += 256) sDs[i] = Wds[i];
    for (int i = tid; i < 128 * 64; i += 256) sDv[i] = Wdv[i];
    __syncthreads();
    int lane = tid & 63, wv = tid >> 6;
    for (int it = 0; it < 4; it++) {
        int n = blockIdx.x * 16 + wv * 4 + it;
        const __half* arow = agg + (size_t)n * 512;
        const float inv_nei = 0.25f;
        float as0 = __half2float(arow[lane]) * inv_nei;
        float as1 = __half2float(arow[64 + lane]) * inv_nei;
        float av00 = __half2float(arow[128 + lane]) * inv_nei;
        float av01 = __half2float(arow[192 + lane]) * inv_nei;
        float av02 = __half2float(arow[256 + lane]) * inv_nei;
        float av10 = __half2float(arow[320 + lane]) * inv_nei;
        float av11 = __half2float(arow[384 + lane]) * inv_nei;
        float av12 = __half2float(arow[448 + lane]) * inv_nei;
        const float* row = nf + (size_t)n * 256;
        float s   = row[lane];
        float vv0 = row[64 + lane * 3 + 0];
        float vv1 = row[64 + lane * 3 + 1];
        float vv2 = row[64 + lane * 3 + 2];

        float f0 = 0.f, f1 = 0.f, fv0 = 0.f, fv1 = 0.f, fv2 = 0.f;
        #pragma unroll 8
        for (int m = 0; m < 64; m++) {
            float am = __shfl(as0, m);
            f0 += am * sDs[m * 128 + lane];
            f1 += am * sDs[m * 128 + 64 + lane];
            float b0 = __shfl(av00, m), b1 = __shfl(av01, m), b2 = __shfl(av02, m);
            float wd = sDv[m * 64 + lane];
            fv0 += b0 * wd; fv1 += b1 * wd; fv2 += b2 * wd;
        }
        #pragma unroll 8
        for (int m = 0; m < 64; m++) {
            float am = __shfl(as1, m);
            f0 += am * sDs[(64 + m) * 128 + lane];
            f1 += am * sDs[(64 + m) * 128 + 64 + lane];
            float b0 = __shfl(av10, m), b1 = __shfl(av11, m), b2 = __shfl(av12, m);
            float wd = sDv[(64 + m) * 64 + lane];
            fv0 += b0 * wd; fv1 += b1 * wd; fv2 += b2 * wd;
        }
        const float inv2m = 0.08838834764831845f;
        f0 *= inv2m; f1 *= inv2m; fv0 *= inv2m; fv1 *= inv2m; fv2 *= inv2m;

        int sp = specie[n];
        if ((unsigned)sp >= 5u) sp = 0;
        const float* Ws = Wss + (size_t)sp * 64 * 128;
        const float* Wv = Wsv + (size_t)sp * 64 * 64;
        float g0 = 0.f, g1 = 0.f, h0 = 0.f, h1 = 0.f, h2 = 0.f;
        #pragma unroll 4
        for (int m = 0; m < 64; m++) {
            float sm = __shfl(s, m);
            g0 += sm * Ws[m * 128 + lane];
            g1 += sm * Ws[m * 128 + 64 + lane];
            float b0 = __shfl(vv0, m), b1 = __shfl(vv1, m), b2 = __shfl(vv2, m);
            float wsk = Wv[m * 64 + lane];
            h0 += b0 * wsk; h1 += b1 * wsk; h2 += b2 * wsk;
        }
        f0 += g0 * 0.125f; f1 += g1 * 0.125f;
        fv0 += h0 * 0.125f; fv1 += h1 * 0.125f; fv2 += h2 * 0.125f;

        float gs   = silu_f(f0);
        float gate = silu_f(f1);
        float* orow = out + (size_t)n * 256;
        orow[lane] = fmaxf(gs, 0.f);
        orow[64 + lane * 3 + 0] = fmaxf(gate * fv0, 0.f);
        orow[64 + lane * 3 + 1] = fmaxf(gate * fv1, 0.f);
        orow[64 + lane * 3 + 2] = fmaxf(gate * fv2, 0.f);
    }
}

// ---------------- Kernel 4b: node tail, f32 agg (fallback path) ----------------
__global__ __launch_bounds__(256) void node_kernel_f(
    const float* __restrict__ nf, const int* __restrict__ specie,
    const float* __restrict__ Wds, const float* __restrict__ Wdv,
    const float* __restrict__ Wss, const float* __restrict__ Wsv,
    const float* __restrict__ agg, float* __restrict__ out)
{
    __shared__ float sDs[128 * 128];
    __shared__ float sDv[128 * 64];
    int tid = threadIdx.x;
    for (int i = tid; i < 128 * 128; i += 256) sDs[i] = Wds[i];
    for (int i = tid; i < 128 * 64; i += 256) sDv[i] = Wdv[i];
    __syncthreads();
    int lane = tid & 63, wv = tid >> 6;
    for (int it = 0; it < 4; it++) {
        int n = blockIdx.x * 16 + wv * 4 + it;
        const float* arow = agg + (size_t)n * 512;
        const float inv_nei = 0.25f;
        float as0 = arow[lane] * inv_nei;
        float as1 = arow[64 + lane] * inv_nei;
        float av00 = arow[128 + lane] * inv_nei;
        float av01 = arow[192 + lane] * inv_nei;
        float av02 = arow[256 + lane] * inv_nei;
        float av10 = arow[320 + lane] * inv_nei;
        float av11 = arow[384 + lane] * inv_nei;
        float av12 = arow[448 + lane] * inv_nei;
        const float* row = nf + (size_t)n * 256;
        float s   = row[lane];
        float vv0 = row[64 + lane * 3 + 0];
        float vv1 = row[64 + lane * 3 + 1];
        float vv2 = row[64 + lane * 3 + 2];

        float f0 = 0.f, f1 = 0.f, fv0 = 0.f, fv1 = 0.f, fv2 = 0.f;
        #pragma unroll 8
        for (int m = 0; m < 64; m++) {
            float am = __shfl(as0, m);
            f0 += am * sDs[m * 128 + lane];
            f1 += am * sDs[m * 128 + 64 + lane];
            float b0 = __shfl(av00, m), b1 = __shfl(av01, m), b2 = __shfl(av02, m);
            float wd = sDv[m * 64 + lane];
            fv0 += b0 * wd; fv1 += b1 * wd; fv2 += b2 * wd;
        }
        #pragma unroll 8
        for (int m = 0; m < 64; m++) {
            float am = __shfl(as1, m);
            f0 += am * sDs[(64 + m) * 128 + lane];
            f1 += am * sDs[(64 + m) * 128 + 64 + lane];
            float b0 = __shfl(av10, m), b1 = __shfl(av11, m), b2 = __shfl(av12, m);
            float wd = sDv[(64 + m) * 64 + lane];
            fv0 += b0 * wd; fv1 += b1 * wd; fv2 += b2 * wd;
        }
        const float inv2m = 0.08838834764831845f;
        f0 *= inv2m; f1 *= inv2m; fv0 *= inv2m; fv1 *= inv2m; fv2 *= inv2m;

        int sp = specie[n];
        if ((unsigned)sp >= 5u) sp = 0;
        const float* Ws = Wss + (size_t)sp * 64 * 128;
        const float* Wv = Wsv + (size_t)sp * 64 * 64;
        float g0 = 0.f, g1 = 0.f, h0 = 0.f, h1 = 0.f, h2 = 0.f;
        #pragma unroll 4
        for (int m = 0; m < 64; m++) {
            float sm = __shfl(s, m);
            g0 += sm * Ws[m * 128 + lane];
            g1 += sm * Ws[m * 128 + 64 + lane];
            float b0 = __shfl(vv0, m), b1 = __shfl(vv1, m), b2 = __shfl(vv2, m);
            float wsk = Wv[m * 64 + lane];
            h0 += b0 * wsk; h1 += b1 * wsk; h2 += b2 * wsk;
        }
        f0 += g0 * 0.125f; f1 += g1 * 0.125f;
        fv0 += h0 * 0.125f; fv1 += h1 * 0.125f; fv2 += h2 * 0.125f;

        float gs   = silu_f(f0);
        float gate = silu_f(f1);
        float* orow = out + (size_t)n * 256;
        orow[lane] = fmaxf(gs, 0.f);
        orow[64 + lane * 3 + 0] = fmaxf(gate * fv0, 0.f);
        orow[64 + lane * 3 + 1] = fmaxf(gate * fv1, 0.f);
        orow[64 + lane * 3 + 2] = fmaxf(gate * fv2, 0.f);
    }
}

// ---------------- Fallback: round-3 fused edge kernel (interleaved up layout) ----------------
__global__ __launch_bounds__(256) void edge_kernel_fb(
    const float* __restrict__ vectors, const float* __restrict__ radial,
    const int* __restrict__ senders, const int* __restrict__ receivers,
    const float* __restrict__ w1, const float* __restrict__ w2,
    const float* __restrict__ w3, const float* __restrict__ wo,
    const float* __restrict__ up, float* __restrict__ agg)
{
    __shared__ __half2 hL[32 * 256];
    __shared__ float   T[16 * 256];
    __shared__ float   sVec[256 * 3];
    __shared__ int     sSnd[256];
    __shared__ int     sRcv[256];

    int tid = threadIdx.x;
    int e = blockIdx.x * 256 + tid;
    int snd = senders[e];
    int rcv = receivers[e];
    if ((unsigned)snd >= (unsigned)NN) snd = 0;
    if ((unsigned)rcv >= (unsigned)NN) rcv = 0;
    float4 ra = *(const float4*)(radial + (size_t)e * 8);
    float4 rb = *(const float4*)(radial + (size_t)e * 8 + 4);
    float vx = vectors[(size_t)e * 3 + 0];
    float vy = vectors[(size_t)e * 3 + 1];
    float vz = vectors[(size_t)e * 3 + 2];
    sSnd[tid] = snd; sRcv[tid] = rcv;
    sVec[tid * 3 + 0] = vx; sVec[tid * 3 + 1] = vy; sVec[tid * 3 + 2] = vz;
    float len2 = vx * vx + vy * vy + vz * vz;
    float mask = (len2 > 0.f) ? 1.f : 0.f;

    {
        float a[64];
        #pragma unroll
        for (int j = 0; j < 64; j++) {
            float acc = ra.x * w1[j]       + ra.y * w1[64 + j]
                      + ra.z * w1[128 + j] + ra.w * w1[192 + j]
                      + rb.x * w1[256 + j] + rb.y * w1[320 + j]
                      + rb.z * w1[384 + j] + rb.w * w1[448 + j];
            a[j] = silu_f(acc * 0.35355339059327373f);
        }
        #pragma unroll
        for (int jp = 0; jp < 32; jp++)
            hL[jp * 256 + tid] = __floats2half2_rn(a[2 * jp], a[2 * jp + 1]);
    }
    {
        float acc[64];
        #pragma unroll
        for (int j = 0; j < 64; j++) acc[j] = 0.f;
        #pragma unroll 2
        for (int kp = 0; kp < 32; kp++) {
            float2 hf = __half22float2(hL[kp * 256 + tid]);
            const float* wr0 = w2 + (size_t)(2 * kp) * 64;
            const float* wr1 = w2 + (size_t)(2 * kp + 1) * 64;
            #pragma unroll
            for (int j = 0; j < 64; j++) acc[j] += hf.x * wr0[j] + hf.y * wr1[j];
        }
        #pragma unroll
        for (int jp = 0; jp < 32; jp++)
            hL[jp * 256 + tid] = __floats2half2_rn(silu_f(acc[2 * jp] * 0.125f),
                                                   silu_f(acc[2 * jp + 1] * 0.125f));
    }
    {
        float acc[64];
        #pragma unroll
        for (int j = 0; j < 64; j++) acc[j] = 0.f;
        #pragma unroll 2
        for (int kp = 0; kp < 32; kp++) {
            float2 hf = __half22float2(hL[kp * 256 + tid]);
            const float* wr0 = w3 + (size_t)(2 * kp) * 64;
            const float* wr1 = w3 + (size_t)(2 * kp + 1) * 64;
            #pragma unroll
            for (int j = 0; j < 64; j++) acc[j] += hf.x * wr0[j] + hf.y * wr1[j];
        }
        #pragma unroll
        for (int jp = 0; jp < 32; jp++)
            hL[jp * 256 + tid] = __floats2half2_rn(silu_f(acc[2 * jp] * 0.125f),
                                                   silu_f(acc[2 * jp + 1] * 0.125f));
    }

    int lane  = tid & 63;
    int wbase = tid & 192;
    int f = lane & 15;
    int g = lane >> 4;

    #define COMPUTE_CHUNK(c, ao)                                                \
        {                                                                       \
            _Pragma("unroll")                                                   \
            for (int j = 0; j < 16; j++) ao[j] = 0.f;                           \
            _Pragma("unroll 4")                                                 \
            for (int kp = 0; kp < 32; kp++) {                                   \
                float2 hf = __half22float2(hL[kp * 256 + tid]);                 \
                const float* wr0 = wo + (size_t)(2 * kp) * 256 + (c) * 16;      \
                const float* wr1 = wo + (size_t)(2 * kp + 1) * 256 + (c) * 16;  \
                _Pragma("unroll")                                               \
                for (int j = 0; j < 16; j++)                                    \
                    ao[j] += hf.x * wr0[j] + hf.y * wr1[j];                     \
            }                                                                   \
            _Pragma("unroll")                                                   \
            for (int j = 0; j < 16; j++) ao[j] *= 0.125f * mask;                \
        }

    #define WRITE_T(ao)                                                         \
        __syncthreads();                                                        \
        _Pragma("unroll")                                                       \
        for (int j = 0; j < 16; j++) T[j * 256 + (tid ^ (2 * j))] = ao[j];      \
        __syncthreads();

    for (int c = 0; c < 4; c++) {
        float ao[16];
        COMPUTE_CHUNK(c, ao)
        WRITE_T(ao)
        for (int el = 0; el < 16; el++) {
            int col = wbase + el * 4 + g;
            int s_ = sSnd[col], rc = sRcv[col];
            float mx = T[f * 256 + (col ^ (2 * f))];
            int jf = c * 16 + f;
            atomicAdd(agg + (size_t)rc * 512 + jf, up[(size_t)s_ * 256 + jf] * mx);
        }
    }
    for (int c = 4; c < 8; c++) {
        float ao[16];
        COMPUTE_CHUNK(c, ao)
        WRITE_T(ao)
        for (int el = 0; el < 16; el++) {
            int col = wbase + el * 4 + g;
            int s_ = sSnd[col], rc = sRcv[col];
            float wx = sVec[col * 3 + 0], wy = sVec[col * 3 + 1], wz = sVec[col * 3 + 2];
            float l2 = wx * wx + wy * wy + wz * wz;
            float il = (l2 > 0.f) ? rsqrtf(l2) : 0.f;
            float mx = T[f * 256 + (col ^ (2 * f))];
            int m = (c - 4) * 16 + f;
            const float* ev = up + (size_t)s_ * 256 + 64 + m * 3;
            float dot = ev[0] * wx + ev[1] * wy + ev[2] * wz;
            atomicAdd(agg + (size_t)rc * 512 + 64 + m, dot * il * mx);
        }
    }
    for (int c = 8; c < 12; c++) {
        float ao[16];
        COMPUTE_CHUNK(c, ao)
        WRITE_T(ao)
        for (int el = 0; el < 16; el++) {
            int col = wbase + el * 4 + g;
            int s_ = sSnd[col], rc = sRcv[col];
            float mx = T[f * 256 + (col ^ (2 * f))];
            int m = (c - 8) * 16 + f;
            const float* ev = up + (size_t)s_ * 256 + 64 + m * 3;
            float* ag = agg + (size_t)rc * 512 + 128 + m;
            atomicAdd(ag + 0,   ev[0] * mx);
            atomicAdd(ag + 64,  ev[1] * mx);
            atomicAdd(ag + 128, ev[2] * mx);
        }
    }
    for (int c = 12; c < 16; c++) {
        float ao[16];
        COMPUTE_CHUNK(c, ao)
        WRITE_T(ao)
        for (int el = 0; el < 16; el++) {
            int col = wbase + el * 4 + g;
            int s_ = sSnd[col], rc = sRcv[col];
            float wx = sVec[col * 3 + 0], wy = sVec[col * 3 + 1], wz = sVec[col * 3 + 2];
            float l2 = wx * wx + wy * wy + wz * wz;
            float il = (l2 > 0.f) ? rsqrtf(l2) : 0.f;
            float mx = T[f * 256 + (col ^ (2 * f))];
            int m = (c - 12) * 16 + f;
            float sc = up[(size_t)s_ * 256 + m] * 1.7320508075688772f * il * mx;
            float* ag = agg + (size_t)rc * 512 + 320 + m;
            atomicAdd(ag + 0,   sc * wx);
            atomicAdd(ag + 64,  sc * wy);
            atomicAdd(ag + 128, sc * wz);
        }
    }
    #undef COMPUTE_CHUNK
    #undef WRITE_T
}

extern "C" void kernel_launch(void* const* d_in, const int* in_sizes, int n_in,
                              void* d_out, int out_size, void* d_ws, size_t ws_size,
                              hipStream_t stream) {
    const float* vectors     = (const float*)d_in[0];
    const float* node_feats  = (const float*)d_in[1];
    const int*   node_specie = (const int*)d_in[2];
    const float* radial      = (const float*)d_in[3];
    const int*   senders     = (const int*)d_in[4];
    const int*   receivers   = (const int*)d_in[5];
    const float* W_up_s      = (const float*)d_in[6];
    const float* W_up_v      = (const float*)d_in[7];
    const float* mlp_w1      = (const float*)d_in[8];
    const float* mlp_w2      = (const float*)d_in[9];
    const float* mlp_w3      = (const float*)d_in[10];
    const float* mlp_wo      = (const float*)d_in[11];
    const float* W_skip_s    = (const float*)d_in[12];
    const float* W_skip_v    = (const float*)d_in[13];
    const float* W_down_s    = (const float*)d_in[14];
    const float* W_down_v    = (const float*)d_in[15];
    float* out = (float*)d_out;

    // workspace: up | agg-region (f32-sized, reused) | mix | wpack
    float* up   = (float*)d_ws;                      // NN*256 f32  = 20.48 MB
    float* aggf = up + (size_t)NN * 256;             // NN*512 f32  = 40.96 MB (fallback)
    __half2* aggh = (__half2*)aggf;                  // NN*256 half2 (primary)
    uintptr_t mix_addr = ((uintptr_t)(aggf + (size_t)NN * 512) + 255) & ~(uintptr_t)255;
    __half* mix = (__half*)mix_addr;                 // EE*256 fp16 = 163.84 MB
    uintptr_t wp_addr = mix_addr + (size_t)EE * 256 * sizeof(__half);  // stays 256B-aligned
    f16* wpack = (f16*)wp_addr;                      // 52*64*8 f16 = 53.2 KB
    size_t required = (size_t)(wp_addr + (size_t)52 * 64 * 8 * sizeof(f16)
                               - (uintptr_t)d_ws);

    if (ws_size >= required) {
        // ---- MFMA MLP + materialized-mix + packed-fp16 atomic scatter ----
        hipMemsetAsync(aggh, 0, (size_t)NN * 512 * sizeof(__half), stream);
        pack_kernel<<<13, 256, 0, stream>>>(mlp_w1, mlp_w2, mlp_w3, mlp_wo, wpack);
        up_kernel<<<NN / 16, 256, 0, stream>>>(node_feats, W_up_s, W_up_v, up, 1);
        mlp_mfma<<<NN / 4, 256, 0, stream>>>(radial, wpack, (f16*)mix);
        scatter_kernel<<<2048, 256, 0, stream>>>(senders, receivers, vectors,
            mix, up, aggh);
        node_kernel_h<<<NN / 16, 256, 0, stream>>>(node_feats, node_specie,
            W_down_s, W_down_v, W_skip_s, W_skip_v, (const __half*)aggh, out);
    } else {
        // ---- fallback: round-3 fused atomic path (f32 agg) ----
        hipMemsetAsync(aggf, 0, (size_t)NN * 512 * sizeof(float), stream);
        up_kernel<<<NN / 16, 256, 0, stream>>>(node_feats, W_up_s, W_up_v, up, 0);
        edge_kernel_fb<<<EE / 256, 256, 0, stream>>>(
            vectors, radial, senders, receivers,
            mlp_w1, mlp_w2, mlp_w3, mlp_wo, up, aggf);
        node_kernel_f<<<NN / 16, 256, 0, stream>>>(node_feats, node_specie,
            W_down_s, W_down_v, W_skip_s, W_skip_v, aggf, out);
    }
}

// Round 10
// 576.884 us; speedup vs baseline: 2.2676x; 1.1041x over previous
//
#include <hip/hip_runtime.h>
#include <hip/hip_fp16.h>

#define NN 20000
#define EE 320000

typedef _Float16 f16;
typedef f16  f16x8 __attribute__((ext_vector_type(8)));
typedef float f32x4 __attribute__((ext_vector_type(4)));

__device__ __forceinline__ float silu_f(float x) {
    return x / (1.0f + __expf(-x));
}

// ---------------- Kernel 1: node up-projection (16 nodes/block) ----------------
__global__ __launch_bounds__(256) void up_kernel(
    const float* __restrict__ nf, const float* __restrict__ Wus,
    const float* __restrict__ Wuv, float* __restrict__ up, int dmajor)
{
    __shared__ float sWs[64 * 64];
    __shared__ float sWv[64 * 64];
    int tid = threadIdx.x;
    for (int i = tid; i < 64 * 64; i += 256) { sWs[i] = Wus[i]; sWv[i] = Wuv[i]; }
    __syncthreads();
    int lane = tid & 63, wv = tid >> 6;
    for (int it = 0; it < 4; it++) {
        int n = blockIdx.x * 16 + wv * 4 + it;
        const float* row = nf + (size_t)n * 256;
        float s  = row[lane];
        float v0 = row[64 + lane * 3 + 0];
        float v1 = row[64 + lane * 3 + 1];
        float v2 = row[64 + lane * 3 + 2];
        float as = 0.f, a0 = 0.f, a1 = 0.f, a2 = 0.f;
        #pragma unroll 8
        for (int m = 0; m < 64; m++) {
            float sm = __shfl(s, m);
            float b0 = __shfl(v0, m), b1 = __shfl(v1, m), b2 = __shfl(v2, m);
            float w_s = sWs[m * 64 + lane];
            float w_v = sWv[m * 64 + lane];
            as += sm * w_s;
            a0 += b0 * w_v; a1 += b1 * w_v; a2 += b2 * w_v;
        }
        float* o = up + (size_t)n * 256;
        if (dmajor) {
            o[lane]       = as * 0.125f;
            o[64  + lane] = a0 * 0.125f;
            o[128 + lane] = a1 * 0.125f;
            o[192 + lane] = a2 * 0.125f;
        } else {
            o[lane] = as * 0.125f;
            o[64 + lane * 3 + 0] = a0 * 0.125f;
            o[64 + lane * 3 + 1] = a1 * 0.125f;
            o[64 + lane * 3 + 2] = a2 * 0.125f;
        }
    }
}

// ---------------- Weight packing into MFMA B-fragment order ----------------
__global__ __launch_bounds__(256) void pack_kernel(
    const float* __restrict__ w1, const float* __restrict__ w2,
    const float* __restrict__ w3, const float* __restrict__ wo,
    f16* __restrict__ wp)
{
    int idx = blockIdx.x * 256 + threadIdx.x;   // 13*256 = 3328 = 52*64
    if (idx >= 52 * 64) return;
    int frag = idx >> 6, lane = idx & 63;
    int col = lane & 15, kg = lane >> 4;
    f16x8 pv;
    if (frag < 4) {
        int t = frag;
        #pragma unroll
        for (int i = 0; i < 8; i++) {
            int k = kg * 8 + i;
            pv[i] = (k < 8) ? (f16)w1[k * 64 + t * 16 + col] : (f16)0.f;
        }
    } else if (frag < 12) {
        int f = frag - 4, t = f >> 1, h = f & 1;
        #pragma unroll
        for (int i = 0; i < 8; i++) {
            int k = h * 32 + kg * 8 + i;
            pv[i] = (f16)w2[k * 64 + t * 16 + col];
        }
    } else if (frag < 20) {
        int f = frag - 12, t = f >> 1, h = f & 1;
        #pragma unroll
        for (int i = 0; i < 8; i++) {
            int k = h * 32 + kg * 8 + i;
            pv[i] = (f16)w3[k * 64 + t * 16 + col];
        }
    } else {
        int f = frag - 20, t = f >> 1, h = f & 1;
        #pragma unroll
        for (int i = 0; i < 8; i++) {
            int k = h * 32 + kg * 8 + i;
            pv[i] = (f16)wo[k * 256 + t * 16 + col];
        }
    }
    *(f16x8*)(wp + (size_t)idx * 8) = pv;
}

// ---------------- Kernel 2: FUSED MFMA edge MLP + packed-fp16 atomic scatter --------
// Wave = 16 edges. MLP via 16x16x32 f16 MFMA; mix tile stays in wave-private LDS
// (outT, XOR-swizzled); scatter phase reads it directly -> no 164MB mix round-trip.
// 48 KiB LDS -> 3 blocks/CU. Scatter is barrier-free, fire-and-forget atomics.
__global__ __launch_bounds__(256) void mlp_scatter(
    const float* __restrict__ radial, const f16* __restrict__ wp,
    const int* __restrict__ senders, const int* __restrict__ receivers,
    const float* __restrict__ vectors, const float* __restrict__ up2,
    __half2* __restrict__ agg)
{
    __shared__ f16 smem[4 * 6144];   // per wave: actA(1024)|actB(1024)|outT(4096)
    int tid = threadIdx.x, lane = tid & 63, w = tid >> 6;
    f16* actA = smem + w * 6144;
    f16* actB = actA + 1024;
    f16* outT = actB + 1024;
    int e0 = (blockIdx.x * 4 + w) * 16;   // EE/64 = 5000 blocks, exact

    int col = lane & 15;
    int kg  = lane >> 4;
    const f32x4 zero = {0.f, 0.f, 0.f, 0.f};

    #define LDB(fr) (*(const f16x8*)(wp + ((size_t)(fr) * 64 + lane) * 8))
    #define LDA(buf, h) (*(const f16x8*)((buf) + (lane & 15) * 64 + \
                        (((kg * 8) + (h) * 32) ^ (((lane & 15) & 7) << 3))))
    #define STACT(buf, acc, SC)                                            \
        _Pragma("unroll")                                                  \
        for (int t = 0; t < 4; t++) {                                      \
            _Pragma("unroll")                                              \
            for (int r = 0; r < 4; r++) {                                  \
                int row = kg * 4 + r;                                      \
                int c   = t * 16 + col;                                    \
                float x = acc[t][r] * (SC);                                \
                (buf)[row * 64 + (c ^ ((row & 7) << 3))] = (f16)silu_f(x); \
            }                                                              \
        }

    // ---- layer 1: 8 -> 64 (K zero-padded to 32) ----
    {
        f16x8 a;
        if (lane < 16) {
            const float* rr = radial + (size_t)(e0 + lane) * 8;
            float4 ra = *(const float4*)rr;
            float4 rb = *(const float4*)(rr + 4);
            a[0] = (f16)ra.x; a[1] = (f16)ra.y; a[2] = (f16)ra.z; a[3] = (f16)ra.w;
            a[4] = (f16)rb.x; a[5] = (f16)rb.y; a[6] = (f16)rb.z; a[7] = (f16)rb.w;
        } else {
            #pragma unroll
            for (int i = 0; i < 8; i++) a[i] = (f16)0.f;
        }
        f32x4 acc[4];
        #pragma unroll
        for (int t = 0; t < 4; t++)
            acc[t] = __builtin_amdgcn_mfma_f32_16x16x32_f16(a, LDB(t), zero, 0, 0, 0);
        STACT(actA, acc, 0.35355339059327373f)
    }
    // ---- layer 2: 64 -> 64 ----
    {
        f16x8 a0 = LDA(actA, 0), a1 = LDA(actA, 1);
        f32x4 acc[4];
        #pragma unroll
        for (int t = 0; t < 4; t++) {
            acc[t] = __builtin_amdgcn_mfma_f32_16x16x32_f16(a0, LDB(4 + t * 2), zero, 0, 0, 0);
            acc[t] = __builtin_amdgcn_mfma_f32_16x16x32_f16(a1, LDB(5 + t * 2), acc[t], 0, 0, 0);
        }
        STACT(actB, acc, 0.125f)
    }
    // ---- layer 3: 64 -> 64 ----
    {
        f16x8 a0 = LDA(actB, 0), a1 = LDA(actB, 1);
        f32x4 acc[4];
        #pragma unroll
        for (int t = 0; t < 4; t++) {
            acc[t] = __builtin_amdgcn_mfma_f32_16x16x32_f16(a0, LDB(12 + t * 2), zero, 0, 0, 0);
            acc[t] = __builtin_amdgcn_mfma_f32_16x16x32_f16(a1, LDB(13 + t * 2), acc[t], 0, 0, 0);
        }
        STACT(actA, acc, 0.125f)
    }
    // ---- output layer: 64 -> 256 into outT (swizzled, wave-private) ----
    {
        f16x8 a0 = LDA(actA, 0), a1 = LDA(actA, 1);
        #pragma unroll
        for (int tg = 0; tg < 4; tg++) {
            f32x4 acc[4];
            #pragma unroll
            for (int q = 0; q < 4; q++) {
                int t = tg * 4 + q;
                acc[q] = __builtin_amdgcn_mfma_f32_16x16x32_f16(a0, LDB(20 + t * 2), zero, 0, 0, 0);
                acc[q] = __builtin_amdgcn_mfma_f32_16x16x32_f16(a1, LDB(21 + t * 2), acc[q], 0, 0, 0);
            }
            #pragma unroll
            for (int q = 0; q < 4; q++) {
                int t = tg * 4 + q;
                #pragma unroll
                for (int r = 0; r < 4; r++) {
                    int row = kg * 4 + r;
                    int c   = t * 16 + col;
                    outT[row * 256 + (c ^ ((row & 7) << 3))] = (f16)(acc[q][r] * 0.125f);
                }
            }
        }
    }

    // ---- scatter phase: wave-private, no barriers ----
    const float SQ3 = 1.7320508075688772f;
    int i  = lane & 31;
    int i2 = i * 2;
    bool lo = (lane < 32);

    for (int el = 0; el < 16; el++) {
        int e = e0 + el;                       // wave-uniform
        int snd = senders[e];
        int rcv = receivers[e];
        if ((unsigned)snd >= (unsigned)NN) snd = 0;
        if ((unsigned)rcv >= (unsigned)NN) rcv = 0;
        float vx = vectors[(size_t)e * 3 + 0];
        float vy = vectors[(size_t)e * 3 + 1];
        float vz = vectors[(size_t)e * 3 + 2];
        float l2 = vx * vx + vy * vy + vz * vz;
        float il   = (l2 > 0.f) ? rsqrtf(l2) : 0.f;
        float mask = (l2 > 0.f) ? 1.f : 0.f;

        int sw = (el & 7) << 3;                // row swizzle for outT
        const f16* orow = outT + el * 256;
        float2 mA = __half22float2(*(const __half2*)(orow + ((i2      ) ^ sw)));
        float2 mB = __half22float2(*(const __half2*)(orow + ((64 + i2) ^ sw)));
        float2 mC = __half22float2(*(const __half2*)(orow + ((128 + i2) ^ sw)));
        float2 mD = __half22float2(*(const __half2*)(orow + ((192 + i2) ^ sw)));
        float mA0 = mA.x * mask, mA1 = mA.y * mask;
        float mB0 = mB.x * mask, mB1 = mB.y * mask;
        float mC0 = mC.x * mask, mC1 = mC.y * mask;
        float mD0 = mD.x * mask, mD1 = mD.y * mask;

        const float* u = up2 + (size_t)snd * 256;
        float2 s2  = *(const float2*)(u + i2);
        float2 ex2 = *(const float2*)(u + 64  + i2);
        float2 ey2 = *(const float2*)(u + 128 + i2);
        float2 ez2 = *(const float2*)(u + 192 + i2);

        float tps0 = (ex2.x * vx + ey2.x * vy + ez2.x * vz) * il;
        float tps1 = (ex2.y * vx + ey2.y * vy + ez2.y * vz) * il;
        float yx = SQ3 * vx * il, yy = SQ3 * vy * il, yz = SQ3 * vz * il;

        float v0x = lo ? s2.x * mA0 : tps0 * mB0;
        float v0y = lo ? s2.y * mA1 : tps1 * mB1;
        float v1x = lo ? ex2.x * mC0 : ey2.x * mC0;
        float v1y = lo ? ex2.y * mC1 : ey2.y * mC1;
        float v2x = lo ? ez2.x * mC0 : s2.x * yx * mD0;
        float v2y = lo ? ez2.y * mC1 : s2.y * yx * mD1;
        float v3x = lo ? s2.x * yy * mD0 : s2.x * yz * mD0;
        float v3y = lo ? s2.y * yy * mD1 : s2.y * yz * mD1;

        __half2* ar = agg + (size_t)rcv * 256;
        unsafeAtomicAdd(ar + lane,       __floats2half2_rn(v0x, v0y));
        unsafeAtomicAdd(ar + 64  + lane, __floats2half2_rn(v1x, v1y));
        unsafeAtomicAdd(ar + 128 + lane, __floats2half2_rn(v2x, v2y));
        unsafeAtomicAdd(ar + 192 + lane, __floats2half2_rn(v3x, v3y));
    }
    #undef LDB
    #undef LDA
    #undef STACT
}

// ---------------- Kernel 4: node tail, fp16 agg (primary path) ----------------
__global__ __launch_bounds__(256) void node_kernel_h(
    const float* __restrict__ nf, const int* __restrict__ specie,
    const float* __restrict__ Wds, const float* __restrict__ Wdv,
    const float* __restrict__ Wss, const float* __restrict__ Wsv,
    const __half* __restrict__ agg, float* __restrict__ out)
{
    __shared__ float sDs[128 * 128];
    __shared__ float sDv[128 * 64];
    int tid = threadIdx.x;
    for (int i = tid; i < 128 * 128; i += 256) sDs[i] = Wds[i];
    for (int i = tid; i < 128 * 64; i += 256) sDv[i] = Wdv[i];
    __syncthreads();
    int lane = tid & 63, wv = tid >> 6;
    for (int it = 0; it < 4; it++) {
        int n = blockIdx.x * 16 + wv * 4 + it;
        const __half* arow = agg + (size_t)n * 512;
        const float inv_nei = 0.25f;
        float as0 = __half2float(arow[lane]) * inv_nei;
        float as1 = __half2float(arow[64 + lane]) * inv_nei;
        float av00 = __half2float(arow[128 + lane]) * inv_nei;
        float av01 = __half2float(arow[192 + lane]) * inv_nei;
        float av02 = __half2float(arow[256 + lane]) * inv_nei;
        float av10 = __half2float(arow[320 + lane]) * inv_nei;
        float av11 = __half2float(arow[384 + lane]) * inv_nei;
        float av12 = __half2float(arow[448 + lane]) * inv_nei;
        const float* row = nf + (size_t)n * 256;
        float s   = row[lane];
        float vv0 = row[64 + lane * 3 + 0];
        float vv1 = row[64 + lane * 3 + 1];
        float vv2 = row[64 + lane * 3 + 2];

        float f0 = 0.f, f1 = 0.f, fv0 = 0.f, fv1 = 0.f, fv2 = 0.f;
        #pragma unroll 8
        for (int m = 0; m < 64; m++) {
            float am = __shfl(as0, m);
            f0 += am * sDs[m * 128 + lane];
            f1 += am * sDs[m * 128 + 64 + lane];
            float b0 = __shfl(av00, m), b1 = __shfl(av01, m), b2 = __shfl(av02, m);
            float wd = sDv[m * 64 + lane];
            fv0 += b0 * wd; fv1 += b1 * wd; fv2 += b2 * wd;
        }
        #pragma unroll 8
        for (int m = 0; m < 64; m++) {
            float am = __shfl(as1, m);
            f0 += am * sDs[(64 + m) * 128 + lane];
            f1 += am * sDs[(64 + m) * 128 + 64 + lane];
            float b0 = __shfl(av10, m), b1 = __shfl(av11, m), b2 = __shfl(av12, m);
            float wd = sDv[(64 + m) * 64 + lane];
            fv0 += b0 * wd; fv1 += b1 * wd; fv2 += b2 * wd;
        }
        const float inv2m = 0.08838834764831845f;
        f0 *= inv2m; f1 *= inv2m; fv0 *= inv2m; fv1 *= inv2m; fv2 *= inv2m;

        int sp = specie[n];
        if ((unsigned)sp >= 5u) sp = 0;
        const float* Ws = Wss + (size_t)sp * 64 * 128;
        const float* Wv = Wsv + (size_t)sp * 64 * 64;
        float g0 = 0.f, g1 = 0.f, h0 = 0.f, h1 = 0.f, h2 = 0.f;
        #pragma unroll 4
        for (int m = 0; m < 64; m++) {
            float sm = __shfl(s, m);
            g0 += sm * Ws[m * 128 + lane];
            g1 += sm * Ws[m * 128 + 64 + lane];
            float b0 = __shfl(vv0, m), b1 = __shfl(vv1, m), b2 = __shfl(vv2, m);
            float wsk = Wv[m * 64 + lane];
            h0 += b0 * wsk; h1 += b1 * wsk; h2 += b2 * wsk;
        }
        f0 += g0 * 0.125f; f1 += g1 * 0.125f;
        fv0 += h0 * 0.125f; fv1 += h1 * 0.125f; fv2 += h2 * 0.125f;

        float gs   = silu_f(f0);
        float gate = silu_f(f1);
        float* orow = out + (size_t)n * 256;
        orow[lane] = fmaxf(gs, 0.f);
        orow[64 + lane * 3 + 0] = fmaxf(gate * fv0, 0.f);
        orow[64 + lane * 3 + 1] = fmaxf(gate * fv1, 0.f);
        orow[64 + lane * 3 + 2] = fmaxf(gate * fv2, 0.f);
    }
}

// ---------------- Kernel 4b: node tail, f32 agg (fallback path) ----------------
__global__ __launch_bounds__(256) void node_kernel_f(
    const float* __restrict__ nf, const int* __restrict__ specie,
    const float* __restrict__ Wds, const float* __restrict__ Wdv,
    const float* __restrict__ Wss, const float* __restrict__ Wsv,
    const float* __restrict__ agg, float* __restrict__ out)
{
    __shared__ float sDs[128 * 128];
    __shared__ float sDv[128 * 64];
    int tid = threadIdx.x;
    for (int i = tid; i < 128 * 128; i += 256) sDs[i] = Wds[i];
    for (int i = tid; i < 128 * 64; i += 256) sDv[i] = Wdv[i];
    __syncthreads();
    int lane = tid & 63, wv = tid >> 6;
    for (int it = 0; it < 4; it++) {
        int n = blockIdx.x * 16 + wv * 4 + it;
        const float* arow = agg + (size_t)n * 512;
        const float inv_nei = 0.25f;
        float as0 = arow[lane] * inv_nei;
        float as1 = arow[64 + lane] * inv_nei;
        float av00 = arow[128 + lane] * inv_nei;
        float av01 = arow[192 + lane] * inv_nei;
        float av02 = arow[256 + lane] * inv_nei;
        float av10 = arow[320 + lane] * inv_nei;
        float av11 = arow[384 + lane] * inv_nei;
        float av12 = arow[448 + lane] * inv_nei;
        const float* row = nf + (size_t)n * 256;
        float s   = row[lane];
        float vv0 = row[64 + lane * 3 + 0];
        float vv1 = row[64 + lane * 3 + 1];
        float vv2 = row[64 + lane * 3 + 2];

        float f0 = 0.f, f1 = 0.f, fv0 = 0.f, fv1 = 0.f, fv2 = 0.f;
        #pragma unroll 8
        for (int m = 0; m < 64; m++) {
            float am = __shfl(as0, m);
            f0 += am * sDs[m * 128 + lane];
            f1 += am * sDs[m * 128 + 64 + lane];
            float b0 = __shfl(av00, m), b1 = __shfl(av01, m), b2 = __shfl(av02, m);
            float wd = sDv[m * 64 + lane];
            fv0 += b0 * wd; fv1 += b1 * wd; fv2 += b2 * wd;
        }
        #pragma unroll 8
        for (int m = 0; m < 64; m++) {
            float am = __shfl(as1, m);
            f0 += am * sDs[(64 + m) * 128 + lane];
            f1 += am * sDs[(64 + m) * 128 + 64 + lane];
            float b0 = __shfl(av10, m), b1 = __shfl(av11, m), b2 = __shfl(av12, m);
            float wd = sDv[(64 + m) * 64 + lane];
            fv0 += b0 * wd; fv1 += b1 * wd; fv2 += b2 * wd;
        }
        const float inv2m = 0.08838834764831845f;
        f0 *= inv2m; f1 *= inv2m; fv0 *= inv2m; fv1 *= inv2m; fv2 *= inv2m;

        int sp = specie[n];
        if ((unsigned)sp >= 5u) sp = 0;
        const float* Ws = Wss + (size_t)sp * 64 * 128;
        const float* Wv = Wsv + (size_t)sp * 64 * 64;
        float g0 = 0.f, g1 = 0.f, h0 = 0.f, h1 = 0.f, h2 = 0.f;
        #pragma unroll 4
        for (int m = 0; m < 64; m++) {
            float sm = __shfl(s, m);
            g0 += sm * Ws[m * 128 + lane];
            g1 += sm * Ws[m * 128 + 64 + lane];
            float b0 = __shfl(vv0, m), b1 = __shfl(vv1, m), b2 = __shfl(vv2, m);
            float wsk = Wv[m * 64 + lane];
            h0 += b0 * wsk; h1 += b1 * wsk; h2 += b2 * wsk;
        }
        f0 += g0 * 0.125f; f1 += g1 * 0.125f;
        fv0 += h0 * 0.125f; fv1 += h1 * 0.125f; fv2 += h2 * 0.125f;

        float gs   = silu_f(f0);
        float gate = silu_f(f1);
        float* orow = out + (size_t)n * 256;
        orow[lane] = fmaxf(gs, 0.f);
        orow[64 + lane * 3 + 0] = fmaxf(gate * fv0, 0.f);
        orow[64 + lane * 3 + 1] = fmaxf(gate * fv1, 0.f);
        orow[64 + lane * 3 + 2] = fmaxf(gate * fv2, 0.f);
    }
}

// ---------------- Fallback: round-3 fused edge kernel (interleaved up layout) ----------------
__global__ __launch_bounds__(256) void edge_kernel_fb(
    const float* __restrict__ vectors, const float* __restrict__ radial,
    const int* __restrict__ senders, const int* __restrict__ receivers,
    const float* __restrict__ w1, const float* __restrict__ w2,
    const float* __restrict__ w3, const float* __restrict__ wo,
    const float* __restrict__ up, float* __restrict__ agg)
{
    __shared__ __half2 hL[32 * 256];
    __shared__ float   T[16 * 256];
    __shared__ float   sVec[256 * 3];
    __shared__ int     sSnd[256];
    __shared__ int     sRcv[256];

    int tid = threadIdx.x;
    int e = blockIdx.x * 256 + tid;
    int snd = senders[e];
    int rcv = receivers[e];
    if ((unsigned)snd >= (unsigned)NN) snd = 0;
    if ((unsigned)rcv >= (unsigned)NN) rcv = 0;
    float4 ra = *(const float4*)(radial + (size_t)e * 8);
    float4 rb = *(const float4*)(radial + (size_t)e * 8 + 4);
    float vx = vectors[(size_t)e * 3 + 0];
    float vy = vectors[(size_t)e * 3 + 1];
    float vz = vectors[(size_t)e * 3 + 2];
    sSnd[tid] = snd; sRcv[tid] = rcv;
    sVec[tid * 3 + 0] = vx; sVec[tid * 3 + 1] = vy; sVec[tid * 3 + 2] = vz;
    float len2 = vx * vx + vy * vy + vz * vz;
    float mask = (len2 > 0.f) ? 1.f : 0.f;

    {
        float a[64];
        #pragma unroll
        for (int j = 0; j < 64; j++) {
            float acc = ra.x * w1[j]       + ra.y * w1[64 + j]
                      + ra.z * w1[128 + j] + ra.w * w1[192 + j]
                      + rb.x * w1[256 + j] + rb.y * w1[320 + j]
                      + rb.z * w1[384 + j] + rb.w * w1[448 + j];
            a[j] = silu_f(acc * 0.35355339059327373f);
        }
        #pragma unroll
        for (int jp = 0; jp < 32; jp++)
            hL[jp * 256 + tid] = __floats2half2_rn(a[2 * jp], a[2 * jp + 1]);
    }
    {
        float acc[64];
        #pragma unroll
        for (int j = 0; j < 64; j++) acc[j] = 0.f;
        #pragma unroll 2
        for (int kp = 0; kp < 32; kp++) {
            float2 hf = __half22float2(hL[kp * 256 + tid]);
            const float* wr0 = w2 + (size_t)(2 * kp) * 64;
            const float* wr1 = w2 + (size_t)(2 * kp + 1) * 64;
            #pragma unroll
            for (int j = 0; j < 64; j++) acc[j] += hf.x * wr0[j] + hf.y * wr1[j];
        }
        #pragma unroll
        for (int jp = 0; jp < 32; jp++)
            hL[jp * 256 + tid] = __floats2half2_rn(silu_f(acc[2 * jp] * 0.125f),
                                                   silu_f(acc[2 * jp + 1] * 0.125f));
    }
    {
        float acc[64];
        #pragma unroll
        for (int j = 0; j < 64; j++) acc[j] = 0.f;
        #pragma unroll 2
        for (int kp = 0; kp < 32; kp++) {
            float2 hf = __half22float2(hL[kp * 256 + tid]);
            const float* wr0 = w3 + (size_t)(2 * kp) * 64;
            const float* wr1 = w3 + (size_t)(2 * kp + 1) * 64;
            #pragma unroll
            for (int j = 0; j < 64; j++) acc[j] += hf.x * wr0[j] + hf.y * wr1[j];
        }
        #pragma unroll
        for (int jp = 0; jp < 32; jp++)
            hL[jp * 256 + tid] = __floats2half2_rn(silu_f(acc[2 * jp] * 0.125f),
                                                   silu_f(acc[2 * jp + 1] * 0.125f));
    }

    int lane  = tid & 63;
    int wbase = tid & 192;
    int f = lane & 15;
    int g = lane >> 4;

    #define COMPUTE_CHUNK(c, ao)                                                \
        {                                                                       \
            _Pragma("unroll")                                                   \
            for (int j = 0; j < 16; j++) ao[j] = 0.f;                           \
            _Pragma("unroll 4")                                                 \
            for (int kp = 0; kp < 32; kp++) {                                   \
                float2 hf = __half22float2(hL[kp * 256 + tid]);                 \
                const float* wr0 = wo + (size_t)(2 * kp) * 256 + (c) * 16;      \
                const float* wr1 = wo + (size_t)(2 * kp + 1) * 256 + (c) * 16;  \
                _Pragma("unroll")                                               \
                for (int j = 0; j < 16; j++)                                    \
                    ao[j] += hf.x * wr0[j] + hf.y * wr1[j];                     \
            }                                                                   \
            _Pragma("unroll")                                                   \
            for (int j = 0; j < 16; j++) ao[j] *= 0.125f * mask;                \
        }

    #define WRITE_T(ao)                                                         \
        __syncthreads();                                                        \
        _Pragma("unroll")                                                       \
        for (int j = 0; j < 16; j++) T[j * 256 + (tid ^ (2 * j))] = ao[j];      \
        __syncthreads();

    for (int c = 0; c < 4; c++) {
        float ao[16];
        COMPUTE_CHUNK(c, ao)
        WRITE_T(ao)
        for (int el = 0; el < 16; el++) {
            int col = wbase + el * 4 + g;
            int s_ = sSnd[col], rc = sRcv[col];
            float mx = T[f * 256 + (col ^ (2 * f))];
            int jf = c * 16 + f;
            atomicAdd(agg + (size_t)rc * 512 + jf, up[(size_t)s_ * 256 + jf] * mx);
        }
    }
    for (int c = 4; c < 8; c++) {
        float ao[16];
        COMPUTE_CHUNK(c, ao)
        WRITE_T(ao)
        for (int el = 0; el < 16; el++) {
            int col = wbase + el * 4 + g;
            int s_ = sSnd[col], rc = sRcv[col];
            float wx = sVec[col * 3 + 0], wy = sVec[col * 3 + 1], wz = sVec[col * 3 + 2];
            float l2 = wx * wx + wy * wy + wz * wz;
            float il = (l2 > 0.f) ? rsqrtf(l2) : 0.f;
            float mx = T[f * 256 + (col ^ (2 * f))];
            int m = (c - 4) * 16 + f;
            const float* ev = up + (size_t)s_ * 256 + 64 + m * 3;
            float dot = ev[0] * wx + ev[1] * wy + ev[2] * wz;
            atomicAdd(agg + (size_t)rc * 512 + 64 + m, dot * il * mx);
        }
    }
    for (int c = 8; c < 12; c++) {
        float ao[16];
        COMPUTE_CHUNK(c, ao)
        WRITE_T(ao)
        for (int el = 0; el < 16; el++) {
            int col = wbase + el * 4 + g;
            int s_ = sSnd[col], rc = sRcv[col];
            float mx = T[f * 256 + (col ^ (2 * f))];
            int m = (c - 8) * 16 + f;
            const float* ev = up + (size_t)s_ * 256 + 64 + m * 3;
            float* ag = agg + (size_t)rc * 512 + 128 + m;
            atomicAdd(ag + 0,   ev[0] * mx);
            atomicAdd(ag + 64,  ev[1] * mx);
            atomicAdd(ag + 128, ev[2] * mx);
        }
    }
    for (int c = 12; c < 16; c++) {
        float ao[16];
        COMPUTE_CHUNK(c, ao)
        WRITE_T(ao)
        for (int el = 0; el < 16; el++) {
            int col = wbase + el * 4 + g;
            int s_ = sSnd[col], rc = sRcv[col];
            float wx = sVec[col * 3 + 0], wy = sVec[col * 3 + 1], wz = sVec[col * 3 + 2];
            float l2 = wx * wx + wy * wy + wz * wz;
            float il = (l2 > 0.f) ? rsqrtf(l2) : 0.f;
            float mx = T[f * 256 + (col ^ (2 * f))];
            int m = (c - 12) * 16 + f;
            float sc = up[(size_t)s_ * 256 + m] * 1.7320508075688772f * il * mx;
            float* ag = agg + (size_t)rc * 512 + 320 + m;
            atomicAdd(ag + 0,   sc * wx);
            atomicAdd(ag + 64,  sc * wy);
            atomicAdd(ag + 128, sc * wz);
        }
    }
    #undef COMPUTE_CHUNK
    #undef WRITE_T
}

extern "C" void kernel_launch(void* const* d_in, const int* in_sizes, int n_in,
                              void* d_out, int out_size, void* d_ws, size_t ws_size,
                              hipStream_t stream) {
    const float* vectors     = (const float*)d_in[0];
    const float* node_feats  = (const float*)d_in[1];
    const int*   node_specie = (const int*)d_in[2];
    const float* radial      = (const float*)d_in[3];
    const int*   senders     = (const int*)d_in[4];
    const int*   receivers   = (const int*)d_in[5];
    const float* W_up_s      = (const float*)d_in[6];
    const float* W_up_v      = (const float*)d_in[7];
    const float* mlp_w1      = (const float*)d_in[8];
    const float* mlp_w2      = (const float*)d_in[9];
    const float* mlp_w3      = (const float*)d_in[10];
    const float* mlp_wo      = (const float*)d_in[11];
    const float* W_skip_s    = (const float*)d_in[12];
    const float* W_skip_v    = (const float*)d_in[13];
    const float* W_down_s    = (const float*)d_in[14];
    const float* W_down_v    = (const float*)d_in[15];
    float* out = (float*)d_out;

    // workspace: up | agg-region (f32-sized, reused) | wpack
    float* up   = (float*)d_ws;                      // NN*256 f32  = 20.48 MB
    float* aggf = up + (size_t)NN * 256;             // NN*512 f32  = 40.96 MB (fallback)
    __half2* aggh = (__half2*)aggf;                  // NN*256 half2 (primary)
    uintptr_t wp_addr = ((uintptr_t)(aggf + (size_t)NN * 512) + 255) & ~(uintptr_t)255;
    f16* wpack = (f16*)wp_addr;                      // 52*64*8 f16 = 53.2 KB
    size_t required = (size_t)(wp_addr + (size_t)52 * 64 * 8 * sizeof(f16)
                               - (uintptr_t)d_ws);

    if (ws_size >= required) {
        // ---- fused MFMA MLP + packed-fp16 atomic scatter ----
        hipMemsetAsync(aggh, 0, (size_t)NN * 512 * sizeof(__half), stream);
        pack_kernel<<<13, 256, 0, stream>>>(mlp_w1, mlp_w2, mlp_w3, mlp_wo, wpack);
        up_kernel<<<NN / 16, 256, 0, stream>>>(node_feats, W_up_s, W_up_v, up, 1);
        mlp_scatter<<<EE / 64, 256, 0, stream>>>(radial, wpack,
            senders, receivers, vectors, up, aggh);
        node_kernel_h<<<NN / 16, 256, 0, stream>>>(node_feats, node_specie,
            W_down_s, W_down_v, W_skip_s, W_skip_v, (const __half*)aggh, out);
    } else {
        // ---- fallback: round-3 fused atomic path (f32 agg) ----
        hipMemsetAsync(aggf, 0, (size_t)NN * 512 * sizeof(float), stream);
        up_kernel<<<NN / 16, 256, 0, stream>>>(node_feats, W_up_s, W_up_v, up, 0);
        edge_kernel_fb<<<EE / 256, 256, 0, stream>>>(
            vectors, radial, senders, receivers,
            mlp_w1, mlp_w2, mlp_w3, mlp_wo, up, aggf);
        node_kernel_f<<<NN / 16, 256, 0, stream>>>(node_feats, node_specie,
            W_down_s, W_down_v, W_skip_s, W_skip_v, aggf, out);
    }
}

// Round 11
// 387.808 us; speedup vs baseline: 3.3732x; 1.4875x over previous
//
#include <hip/hip_runtime.h>
#include <hip/hip_fp16.h>

#define NN 20000
#define EE 320000

typedef _Float16 f16;
typedef f16  f16x8 __attribute__((ext_vector_type(8)));
typedef float f32x4 __attribute__((ext_vector_type(4)));

__device__ __forceinline__ float silu_f(float x) {
    return x / (1.0f + __expf(-x));
}

// ---------------- Kernel 1: node up-projection (16 nodes/block) ----------------
__global__ __launch_bounds__(256) void up_kernel(
    const float* __restrict__ nf, const float* __restrict__ Wus,
    const float* __restrict__ Wuv, float* __restrict__ up, int dmajor)
{
    __shared__ float sWs[64 * 64];
    __shared__ float sWv[64 * 64];
    int tid = threadIdx.x;
    for (int i = tid; i < 64 * 64; i += 256) { sWs[i] = Wus[i]; sWv[i] = Wuv[i]; }
    __syncthreads();
    int lane = tid & 63, wv = tid >> 6;
    for (int it = 0; it < 4; it++) {
        int n = blockIdx.x * 16 + wv * 4 + it;
        const float* row = nf + (size_t)n * 256;
        float s  = row[lane];
        float v0 = row[64 + lane * 3 + 0];
        float v1 = row[64 + lane * 3 + 1];
        float v2 = row[64 + lane * 3 + 2];
        float as = 0.f, a0 = 0.f, a1 = 0.f, a2 = 0.f;
        #pragma unroll 8
        for (int m = 0; m < 64; m++) {
            float sm = __shfl(s, m);
            float b0 = __shfl(v0, m), b1 = __shfl(v1, m), b2 = __shfl(v2, m);
            float w_s = sWs[m * 64 + lane];
            float w_v = sWv[m * 64 + lane];
            as += sm * w_s;
            a0 += b0 * w_v; a1 += b1 * w_v; a2 += b2 * w_v;
        }
        float* o = up + (size_t)n * 256;
        if (dmajor) {
            o[lane]       = as * 0.125f;
            o[64  + lane] = a0 * 0.125f;
            o[128 + lane] = a1 * 0.125f;
            o[192 + lane] = a2 * 0.125f;
        } else {
            o[lane] = as * 0.125f;
            o[64 + lane * 3 + 0] = a0 * 0.125f;
            o[64 + lane * 3 + 1] = a1 * 0.125f;
            o[64 + lane * 3 + 2] = a2 * 0.125f;
        }
    }
}

// ---------------- MLP weight packing into MFMA B-fragment order ----------------
__global__ __launch_bounds__(256) void pack_kernel(
    const float* __restrict__ w1, const float* __restrict__ w2,
    const float* __restrict__ w3, const float* __restrict__ wo,
    f16* __restrict__ wp)
{
    int idx = blockIdx.x * 256 + threadIdx.x;   // 13*256 = 3328 = 52*64
    if (idx >= 52 * 64) return;
    int frag = idx >> 6, lane = idx & 63;
    int col = lane & 15, kg = lane >> 4;
    f16x8 pv;
    if (frag < 4) {
        int t = frag;
        #pragma unroll
        for (int i = 0; i < 8; i++) {
            int k = kg * 8 + i;
            pv[i] = (k < 8) ? (f16)w1[k * 64 + t * 16 + col] : (f16)0.f;
        }
    } else if (frag < 12) {
        int f = frag - 4, t = f >> 1, h = f & 1;
        #pragma unroll
        for (int i = 0; i < 8; i++) {
            int k = h * 32 + kg * 8 + i;
            pv[i] = (f16)w2[k * 64 + t * 16 + col];
        }
    } else if (frag < 20) {
        int f = frag - 12, t = f >> 1, h = f & 1;
        #pragma unroll
        for (int i = 0; i < 8; i++) {
            int k = h * 32 + kg * 8 + i;
            pv[i] = (f16)w3[k * 64 + t * 16 + col];
        }
    } else {
        int f = frag - 20, t = f >> 1, h = f & 1;
        #pragma unroll
        for (int i = 0; i < 8; i++) {
            int k = h * 32 + kg * 8 + i;
            pv[i] = (f16)wo[k * 256 + t * 16 + col];
        }
    }
    *(f16x8*)(wp + (size_t)idx * 8) = pv;
}

// ---------------- Node weight packing (down + per-specie skip), scales folded ----
// frag ids: 0-31 DS(t0-7,kf0-3) | 32-47 DV(t0-3,kf0-3) |
//           48-127 SS(sp,t0-7,kf0-1) | 128-167 SV(sp,t0-3,kf0-1)
__global__ __launch_bounds__(256) void pack2_kernel(
    const float* __restrict__ Wds, const float* __restrict__ Wdv,
    const float* __restrict__ Wss, const float* __restrict__ Wsv,
    f16* __restrict__ wp2)
{
    int idx = blockIdx.x * 256 + threadIdx.x;   // 42*256 >= 168*64
    if (idx >= 168 * 64) return;
    int frag = idx >> 6, lane = idx & 63;
    int col = lane & 15, kg = lane >> 4;
    const float S_d = 0.25f * 0.08838834764831845f;   // inv_nei * inv2m
    const float S_k = 0.125f;                          // inv_m
    f16x8 pv;
    if (frag < 32) {
        int t = frag >> 2, kf = frag & 3;
        #pragma unroll
        for (int i = 0; i < 8; i++) {
            int k = kf * 32 + kg * 8 + i;
            pv[i] = (f16)(Wds[k * 128 + t * 16 + col] * S_d);
        }
    } else if (frag < 48) {
        int f = frag - 32; int t = f >> 2, kf = f & 3;
        #pragma unroll
        for (int i = 0; i < 8; i++) {
            int k = kf * 32 + kg * 8 + i;
            pv[i] = (f16)(Wdv[k * 64 + t * 16 + col] * S_d);
        }
    } else if (frag < 128) {
        int f = frag - 48; int sp = f >> 4; int t = (f & 15) >> 1; int kf = f & 1;
        #pragma unroll
        for (int i = 0; i < 8; i++) {
            int k = kf * 32 + kg * 8 + i;
            pv[i] = (f16)(Wss[((size_t)sp * 64 + k) * 128 + t * 16 + col] * S_k);
        }
    } else {
        int f = frag - 128; int sp = f >> 3; int t = (f & 7) >> 1; int kf = f & 1;
        #pragma unroll
        for (int i = 0; i < 8; i++) {
            int k = kf * 32 + kg * 8 + i;
            pv[i] = (f16)(Wsv[((size_t)sp * 64 + k) * 64 + t * 16 + col] * S_k);
        }
    }
    *(f16x8*)(wp2 + (size_t)idx * 8) = pv;
}

// ---------------- Kernel 2: FUSED MFMA edge MLP + packed-fp16 atomic scatter --------
__global__ __launch_bounds__(256) void mlp_scatter(
    const float* __restrict__ radial, const f16* __restrict__ wp,
    const int* __restrict__ senders, const int* __restrict__ receivers,
    const float* __restrict__ vectors, const float* __restrict__ up2,
    __half2* __restrict__ agg)
{
    __shared__ f16 smem[4 * 6144];   // per wave: actA(1024)|actB(1024)|outT(4096)
    int tid = threadIdx.x, lane = tid & 63, w = tid >> 6;
    f16* actA = smem + w * 6144;
    f16* actB = actA + 1024;
    f16* outT = actB + 1024;
    int e0 = (blockIdx.x * 4 + w) * 16;

    int col = lane & 15;
    int kg  = lane >> 4;
    const f32x4 zero = {0.f, 0.f, 0.f, 0.f};

    #define LDB(fr) (*(const f16x8*)(wp + ((size_t)(fr) * 64 + lane) * 8))
    #define LDA(buf, h) (*(const f16x8*)((buf) + (lane & 15) * 64 + \
                        (((kg * 8) + (h) * 32) ^ (((lane & 15) & 7) << 3))))
    #define STACT(buf, acc, SC)                                            \
        _Pragma("unroll")                                                  \
        for (int t = 0; t < 4; t++) {                                      \
            _Pragma("unroll")                                              \
            for (int r = 0; r < 4; r++) {                                  \
                int row = kg * 4 + r;                                      \
                int c   = t * 16 + col;                                    \
                float x = acc[t][r] * (SC);                                \
                (buf)[row * 64 + (c ^ ((row & 7) << 3))] = (f16)silu_f(x); \
            }                                                              \
        }

    {
        f16x8 a;
        if (lane < 16) {
            const float* rr = radial + (size_t)(e0 + lane) * 8;
            float4 ra = *(const float4*)rr;
            float4 rb = *(const float4*)(rr + 4);
            a[0] = (f16)ra.x; a[1] = (f16)ra.y; a[2] = (f16)ra.z; a[3] = (f16)ra.w;
            a[4] = (f16)rb.x; a[5] = (f16)rb.y; a[6] = (f16)rb.z; a[7] = (f16)rb.w;
        } else {
            #pragma unroll
            for (int i = 0; i < 8; i++) a[i] = (f16)0.f;
        }
        f32x4 acc[4];
        #pragma unroll
        for (int t = 0; t < 4; t++)
            acc[t] = __builtin_amdgcn_mfma_f32_16x16x32_f16(a, LDB(t), zero, 0, 0, 0);
        STACT(actA, acc, 0.35355339059327373f)
    }
    {
        f16x8 a0 = LDA(actA, 0), a1 = LDA(actA, 1);
        f32x4 acc[4];
        #pragma unroll
        for (int t = 0; t < 4; t++) {
            acc[t] = __builtin_amdgcn_mfma_f32_16x16x32_f16(a0, LDB(4 + t * 2), zero, 0, 0, 0);
            acc[t] = __builtin_amdgcn_mfma_f32_16x16x32_f16(a1, LDB(5 + t * 2), acc[t], 0, 0, 0);
        }
        STACT(actB, acc, 0.125f)
    }
    {
        f16x8 a0 = LDA(actB, 0), a1 = LDA(actB, 1);
        f32x4 acc[4];
        #pragma unroll
        for (int t = 0; t < 4; t++) {
            acc[t] = __builtin_amdgcn_mfma_f32_16x16x32_f16(a0, LDB(12 + t * 2), zero, 0, 0, 0);
            acc[t] = __builtin_amdgcn_mfma_f32_16x16x32_f16(a1, LDB(13 + t * 2), acc[t], 0, 0, 0);
        }
        STACT(actA, acc, 0.125f)
    }
    {
        f16x8 a0 = LDA(actA, 0), a1 = LDA(actA, 1);
        #pragma unroll
        for (int tg = 0; tg < 4; tg++) {
            f32x4 acc[4];
            #pragma unroll
            for (int q = 0; q < 4; q++) {
                int t = tg * 4 + q;
                acc[q] = __builtin_amdgcn_mfma_f32_16x16x32_f16(a0, LDB(20 + t * 2), zero, 0, 0, 0);
                acc[q] = __builtin_amdgcn_mfma_f32_16x16x32_f16(a1, LDB(21 + t * 2), acc[q], 0, 0, 0);
            }
            #pragma unroll
            for (int q = 0; q < 4; q++) {
                int t = tg * 4 + q;
                #pragma unroll
                for (int r = 0; r < 4; r++) {
                    int row = kg * 4 + r;
                    int c   = t * 16 + col;
                    outT[row * 256 + (c ^ ((row & 7) << 3))] = (f16)(acc[q][r] * 0.125f);
                }
            }
        }
    }

    const float SQ3 = 1.7320508075688772f;
    int i  = lane & 31;
    int i2 = i * 2;
    bool lo = (lane < 32);

    for (int el = 0; el < 16; el++) {
        int e = e0 + el;
        int snd = senders[e];
        int rcv = receivers[e];
        if ((unsigned)snd >= (unsigned)NN) snd = 0;
        if ((unsigned)rcv >= (unsigned)NN) rcv = 0;
        float vx = vectors[(size_t)e * 3 + 0];
        float vy = vectors[(size_t)e * 3 + 1];
        float vz = vectors[(size_t)e * 3 + 2];
        float l2 = vx * vx + vy * vy + vz * vz;
        float il   = (l2 > 0.f) ? rsqrtf(l2) : 0.f;
        float mask = (l2 > 0.f) ? 1.f : 0.f;

        int sw = (el & 7) << 3;
        const f16* orow = outT + el * 256;
        float2 mA = __half22float2(*(const __half2*)(orow + ((i2      ) ^ sw)));
        float2 mB = __half22float2(*(const __half2*)(orow + ((64 + i2) ^ sw)));
        float2 mC = __half22float2(*(const __half2*)(orow + ((128 + i2) ^ sw)));
        float2 mD = __half22float2(*(const __half2*)(orow + ((192 + i2) ^ sw)));
        float mA0 = mA.x * mask, mA1 = mA.y * mask;
        float mB0 = mB.x * mask, mB1 = mB.y * mask;
        float mC0 = mC.x * mask, mC1 = mC.y * mask;
        float mD0 = mD.x * mask, mD1 = mD.y * mask;

        const float* u = up2 + (size_t)snd * 256;
        float2 s2  = *(const float2*)(u + i2);
        float2 ex2 = *(const float2*)(u + 64  + i2);
        float2 ey2 = *(const float2*)(u + 128 + i2);
        float2 ez2 = *(const float2*)(u + 192 + i2);

        float tps0 = (ex2.x * vx + ey2.x * vy + ez2.x * vz) * il;
        float tps1 = (ex2.y * vx + ey2.y * vy + ez2.y * vz) * il;
        float yx = SQ3 * vx * il, yy = SQ3 * vy * il, yz = SQ3 * vz * il;

        float v0x = lo ? s2.x * mA0 : tps0 * mB0;
        float v0y = lo ? s2.y * mA1 : tps1 * mB1;
        float v1x = lo ? ex2.x * mC0 : ey2.x * mC0;
        float v1y = lo ? ex2.y * mC1 : ey2.y * mC1;
        float v2x = lo ? ez2.x * mC0 : s2.x * yx * mD0;
        float v2y = lo ? ez2.y * mC1 : s2.y * yx * mD1;
        float v3x = lo ? s2.x * yy * mD0 : s2.x * yz * mD0;
        float v3y = lo ? s2.y * yy * mD1 : s2.y * yz * mD1;

        __half2* ar = agg + (size_t)rcv * 256;
        unsafeAtomicAdd(ar + lane,       __floats2half2_rn(v0x, v0y));
        unsafeAtomicAdd(ar + 64  + lane, __floats2half2_rn(v1x, v1y));
        unsafeAtomicAdd(ar + 128 + lane, __floats2half2_rn(v2x, v2y));
        unsafeAtomicAdd(ar + 192 + lane, __floats2half2_rn(v3x, v3y));
    }
    #undef LDB
    #undef LDA
    #undef STACT
}

// ---------------- Kernel 4: MFMA node tail (no LDS, no shuffles) ----------------
// Wave = 16 nodes. f = agg@Wd' + masked-specie(s,v)@Ws'; scales pre-folded into B.
// A frags read directly from fp16 d-major agg and from nf (float4 -> f16 cvt).
__global__ __launch_bounds__(256) void node_mfma(
    const float* __restrict__ nf, const int* __restrict__ specie,
    const f16* __restrict__ wp2, const f16* __restrict__ agg,
    float* __restrict__ out)
{
    int tid = threadIdx.x, lane = tid & 63, w = tid >> 6;
    int n0 = (blockIdx.x * 4 + w) * 16;
    if (n0 >= NN) return;
    int col = lane & 15, kg = lane >> 4;
    int myn = n0 + col;                       // A-row node for this lane
    int mysp = specie[myn];
    if ((unsigned)mysp >= 5u) mysp = 0;
    const f32x4 zero = {0.f, 0.f, 0.f, 0.f};
    const f16x8 zv = {};

    #define LDB2(fr) (*(const f16x8*)(wp2 + ((size_t)(fr) * 64 + lane) * 8))

    // ---- scalar GEMM: f_s[16 x 128] = agg_s@DS' + s@SS'[sp] ----
    f32x4 accs[8];
    #pragma unroll
    for (int t = 0; t < 8; t++) accs[t] = zero;
    #pragma unroll
    for (int kf = 0; kf < 4; kf++) {
        f16x8 a = *(const f16x8*)(agg + (size_t)myn * 512 + kf * 32 + kg * 8);
        #pragma unroll
        for (int t = 0; t < 8; t++)
            accs[t] = __builtin_amdgcn_mfma_f32_16x16x32_f16(a, LDB2(t * 4 + kf), accs[t], 0, 0, 0);
    }
    #pragma unroll
    for (int kf = 0; kf < 2; kf++) {
        const float* base = nf + (size_t)myn * 256 + kf * 32 + kg * 8;
        float4 x0 = *(const float4*)(base);
        float4 x1 = *(const float4*)(base + 4);
        f16x8 a;
        a[0] = (f16)x0.x; a[1] = (f16)x0.y; a[2] = (f16)x0.z; a[3] = (f16)x0.w;
        a[4] = (f16)x1.x; a[5] = (f16)x1.y; a[6] = (f16)x1.z; a[7] = (f16)x1.w;
        #pragma unroll
        for (int sp = 0; sp < 5; sp++) {
            f16x8 am = (mysp == sp) ? a : zv;
            #pragma unroll
            for (int t = 0; t < 8; t++)
                accs[t] = __builtin_amdgcn_mfma_f32_16x16x32_f16(am, LDB2(48 + sp * 16 + t * 2 + kf), accs[t], 0, 0, 0);
        }
    }
    // scalar epilogue: tiles 0-3 -> gated_s, tiles 4-7 -> gates
    float gates[4][4];
    #pragma unroll
    for (int t = 0; t < 4; t++) {
        #pragma unroll
        for (int r = 0; r < 4; r++) {
            int n = n0 + kg * 4 + r;
            out[(size_t)n * 256 + t * 16 + col] = fmaxf(silu_f(accs[t][r]), 0.f);
            gates[t][r] = silu_f(accs[4 + t][r]);
        }
    }

    // ---- vector GEMMs, per component c ----
    #pragma unroll
    for (int c = 0; c < 3; c++) {
        f32x4 accv[4];
        #pragma unroll
        for (int t = 0; t < 4; t++) accv[t] = zero;
        #pragma unroll
        for (int kf = 0; kf < 4; kf++) {
            int off = (kf < 2) ? (128 + c * 64 + kf * 32) : (320 + c * 64 + (kf - 2) * 32);
            f16x8 a = *(const f16x8*)(agg + (size_t)myn * 512 + off + kg * 8);
            #pragma unroll
            for (int t = 0; t < 4; t++)
                accv[t] = __builtin_amdgcn_mfma_f32_16x16x32_f16(a, LDB2(32 + t * 4 + kf), accv[t], 0, 0, 0);
        }
        #pragma unroll
        for (int kf = 0; kf < 2; kf++) {
            const float* base = nf + (size_t)myn * 256 + 64 + (kf * 32 + kg * 8) * 3;
            float4 q0 = *(const float4*)(base);
            float4 q1 = *(const float4*)(base + 4);
            float4 q2 = *(const float4*)(base + 8);
            float4 q3 = *(const float4*)(base + 12);
            float4 q4 = *(const float4*)(base + 16);
            float4 q5 = *(const float4*)(base + 20);
            float qa[24] = {q0.x, q0.y, q0.z, q0.w, q1.x, q1.y, q1.z, q1.w,
                            q2.x, q2.y, q2.z, q2.w, q3.x, q3.y, q3.z, q3.w,
                            q4.x, q4.y, q4.z, q4.w, q5.x, q5.y, q5.z, q5.w};
            f16x8 a;
            #pragma unroll
            for (int i = 0; i < 8; i++) a[i] = (f16)qa[i * 3 + c];
            #pragma unroll
            for (int sp = 0; sp < 5; sp++) {
                f16x8 am = (mysp == sp) ? a : zv;
                #pragma unroll
                for (int t = 0; t < 4; t++)
                    accv[t] = __builtin_amdgcn_mfma_f32_16x16x32_f16(am, LDB2(128 + sp * 8 + t * 2 + kf), accv[t], 0, 0, 0);
            }
        }
        #pragma unroll
        for (int t = 0; t < 4; t++) {
            #pragma unroll
            for (int r = 0; r < 4; r++) {
                int n = n0 + kg * 4 + r;
                out[(size_t)n * 256 + 64 + (t * 16 + col) * 3 + c] =
                    fmaxf(gates[t][r] * accv[t][r], 0.f);
            }
        }
    }
    #undef LDB2
}

// ---------------- Kernel 4b: node tail, f32 agg (fallback path) ----------------
__global__ __launch_bounds__(256) void node_kernel_f(
    const float* __restrict__ nf, const int* __restrict__ specie,
    const float* __restrict__ Wds, const float* __restrict__ Wdv,
    const float* __restrict__ Wss, const float* __restrict__ Wsv,
    const float* __restrict__ agg, float* __restrict__ out)
{
    __shared__ float sDs[128 * 128];
    __shared__ float sDv[128 * 64];
    int tid = threadIdx.x;
    for (int i = tid; i < 128 * 128; i += 256) sDs[i] = Wds[i];
    for (int i = tid; i < 128 * 64; i += 256) sDv[i] = Wdv[i];
    __syncthreads();
    int lane = tid & 63, wv = tid >> 6;
    for (int it = 0; it < 4; it++) {
        int n = blockIdx.x * 16 + wv * 4 + it;
        const float* arow = agg + (size_t)n * 512;
        const float inv_nei = 0.25f;
        float as0 = arow[lane] * inv_nei;
        float as1 = arow[64 + lane] * inv_nei;
        float av00 = arow[128 + lane] * inv_nei;
        float av01 = arow[192 + lane] * inv_nei;
        float av02 = arow[256 + lane] * inv_nei;
        float av10 = arow[320 + lane] * inv_nei;
        float av11 = arow[384 + lane] * inv_nei;
        float av12 = arow[448 + lane] * inv_nei;
        const float* row = nf + (size_t)n * 256;
        float s   = row[lane];
        float vv0 = row[64 + lane * 3 + 0];
        float vv1 = row[64 + lane * 3 + 1];
        float vv2 = row[64 + lane * 3 + 2];

        float f0 = 0.f, f1 = 0.f, fv0 = 0.f, fv1 = 0.f, fv2 = 0.f;
        #pragma unroll 8
        for (int m = 0; m < 64; m++) {
            float am = __shfl(as0, m);
            f0 += am * sDs[m * 128 + lane];
            f1 += am * sDs[m * 128 + 64 + lane];
            float b0 = __shfl(av00, m), b1 = __shfl(av01, m), b2 = __shfl(av02, m);
            float wd = sDv[m * 64 + lane];
            fv0 += b0 * wd; fv1 += b1 * wd; fv2 += b2 * wd;
        }
        #pragma unroll 8
        for (int m = 0; m < 64; m++) {
            float am = __shfl(as1, m);
            f0 += am * sDs[(64 + m) * 128 + lane];
            f1 += am * sDs[(64 + m) * 128 + 64 + lane];
            float b0 = __shfl(av10, m), b1 = __shfl(av11, m), b2 = __shfl(av12, m);
            float wd = sDv[(64 + m) * 64 + lane];
            fv0 += b0 * wd; fv1 += b1 * wd; fv2 += b2 * wd;
        }
        const float inv2m = 0.08838834764831845f;
        f0 *= inv2m; f1 *= inv2m; fv0 *= inv2m; fv1 *= inv2m; fv2 *= inv2m;

        int sp = specie[n];
        if ((unsigned)sp >= 5u) sp = 0;
        const float* Ws = Wss + (size_t)sp * 64 * 128;
        const float* Wv = Wsv + (size_t)sp * 64 * 64;
        float g0 = 0.f, g1 = 0.f, h0 = 0.f, h1 = 0.f, h2 = 0.f;
        #pragma unroll 4
        for (int m = 0; m < 64; m++) {
            float sm = __shfl(s, m);
            g0 += sm * Ws[m * 128 + lane];
            g1 += sm * Ws[m * 128 + 64 + lane];
            float b0 = __shfl(vv0, m), b1 = __shfl(vv1, m), b2 = __shfl(vv2, m);
            float wsk = Wv[m * 64 + lane];
            h0 += b0 * wsk; h1 += b1 * wsk; h2 += b2 * wsk;
        }
        f0 += g0 * 0.125f; f1 += g1 * 0.125f;
        fv0 += h0 * 0.125f; fv1 += h1 * 0.125f; fv2 += h2 * 0.125f;

        float gs   = silu_f(f0);
        float gate = silu_f(f1);
        float* orow = out + (size_t)n * 256;
        orow[lane] = fmaxf(gs, 0.f);
        orow[64 + lane * 3 + 0] = fmaxf(gate * fv0, 0.f);
        orow[64 + lane * 3 + 1] = fmaxf(gate * fv1, 0.f);
        orow[64 + lane * 3 + 2] = fmaxf(gate * fv2, 0.f);
    }
}

// ---------------- Fallback: round-3 fused edge kernel (interleaved up layout) ----------------
__global__ __launch_bounds__(256) void edge_kernel_fb(
    const float* __restrict__ vectors, const float* __restrict__ radial,
    const int* __restrict__ senders, const int* __restrict__ receivers,
    const float* __restrict__ w1, const float* __restrict__ w2,
    const float* __restrict__ w3, const float* __restrict__ wo,
    const float* __restrict__ up, float* __restrict__ agg)
{
    __shared__ __half2 hL[32 * 256];
    __shared__ float   T[16 * 256];
    __shared__ float   sVec[256 * 3];
    __shared__ int     sSnd[256];
    __shared__ int     sRcv[256];

    int tid = threadIdx.x;
    int e = blockIdx.x * 256 + tid;
    int snd = senders[e];
    int rcv = receivers[e];
    if ((unsigned)snd >= (unsigned)NN) snd = 0;
    if ((unsigned)rcv >= (unsigned)NN) rcv = 0;
    float4 ra = *(const float4*)(radial + (size_t)e * 8);
    float4 rb = *(const float4*)(radial + (size_t)e * 8 + 4);
    float vx = vectors[(size_t)e * 3 + 0];
    float vy = vectors[(size_t)e * 3 + 1];
    float vz = vectors[(size_t)e * 3 + 2];
    sSnd[tid] = snd; sRcv[tid] = rcv;
    sVec[tid * 3 + 0] = vx; sVec[tid * 3 + 1] = vy; sVec[tid * 3 + 2] = vz;
    float len2 = vx * vx + vy * vy + vz * vz;
    float mask = (len2 > 0.f) ? 1.f : 0.f;

    {
        float a[64];
        #pragma unroll
        for (int j = 0; j < 64; j++) {
            float acc = ra.x * w1[j]       + ra.y * w1[64 + j]
                      + ra.z * w1[128 + j] + ra.w * w1[192 + j]
                      + rb.x * w1[256 + j] + rb.y * w1[320 + j]
                      + rb.z * w1[384 + j] + rb.w * w1[448 + j];
            a[j] = silu_f(acc * 0.35355339059327373f);
        }
        #pragma unroll
        for (int jp = 0; jp < 32; jp++)
            hL[jp * 256 + tid] = __floats2half2_rn(a[2 * jp], a[2 * jp + 1]);
    }
    {
        float acc[64];
        #pragma unroll
        for (int j = 0; j < 64; j++) acc[j] = 0.f;
        #pragma unroll 2
        for (int kp = 0; kp < 32; kp++) {
            float2 hf = __half22float2(hL[kp * 256 + tid]);
            const float* wr0 = w2 + (size_t)(2 * kp) * 64;
            const float* wr1 = w2 + (size_t)(2 * kp + 1) * 64;
            #pragma unroll
            for (int j = 0; j < 64; j++) acc[j] += hf.x * wr0[j] + hf.y * wr1[j];
        }
        #pragma unroll
        for (int jp = 0; jp < 32; jp++)
            hL[jp * 256 + tid] = __floats2half2_rn(silu_f(acc[2 * jp] * 0.125f),
                                                   silu_f(acc[2 * jp + 1] * 0.125f));
    }
    {
        float acc[64];
        #pragma unroll
        for (int j = 0; j < 64; j++) acc[j] = 0.f;
        #pragma unroll 2
        for (int kp = 0; kp < 32; kp++) {
            float2 hf = __half22float2(hL[kp * 256 + tid]);
            const float* wr0 = w3 + (size_t)(2 * kp) * 64;
            const float* wr1 = w3 + (size_t)(2 * kp + 1) * 64;
            #pragma unroll
            for (int j = 0; j < 64; j++) acc[j] += hf.x * wr0[j] + hf.y * wr1[j];
        }
        #pragma unroll
        for (int jp = 0; jp < 32; jp++)
            hL[jp * 256 + tid] = __floats2half2_rn(silu_f(acc[2 * jp] * 0.125f),
                                                   silu_f(acc[2 * jp + 1] * 0.125f));
    }

    int lane  = tid & 63;
    int wbase = tid & 192;
    int f = lane & 15;
    int g = lane >> 4;

    #define COMPUTE_CHUNK(c, ao)                                                \
        {                                                                       \
            _Pragma("unroll")                                                   \
            for (int j = 0; j < 16; j++) ao[j] = 0.f;                           \
            _Pragma("unroll 4")                                                 \
            for (int kp = 0; kp < 32; kp++) {                                   \
                float2 hf = __half22float2(hL[kp * 256 + tid]);                 \
                const float* wr0 = wo + (size_t)(2 * kp) * 256 + (c) * 16;      \
                const float* wr1 = wo + (size_t)(2 * kp + 1) * 256 + (c) * 16;  \
                _Pragma("unroll")                                               \
                for (int j = 0; j < 16; j++)                                    \
                    ao[j] += hf.x * wr0[j] + hf.y * wr1[j];                     \
            }                                                                   \
            _Pragma("unroll")                                                   \
            for (int j = 0; j < 16; j++) ao[j] *= 0.125f * mask;                \
        }

    #define WRITE_T(ao)                                                         \
        __syncthreads();                                                        \
        _Pragma("unroll")                                                       \
        for (int j = 0; j < 16; j++) T[j * 256 + (tid ^ (2 * j))] = ao[j];      \
        __syncthreads();

    for (int c = 0; c < 4; c++) {
        float ao[16];
        COMPUTE_CHUNK(c, ao)
        WRITE_T(ao)
        for (int el = 0; el < 16; el++) {
            int col = wbase + el * 4 + g;
            int s_ = sSnd[col], rc = sRcv[col];
            float mx = T[f * 256 + (col ^ (2 * f))];
            int jf = c * 16 + f;
            atomicAdd(agg + (size_t)rc * 512 + jf, up[(size_t)s_ * 256 + jf] * mx);
        }
    }
    for (int c = 4; c < 8; c++) {
        float ao[16];
        COMPUTE_CHUNK(c, ao)
        WRITE_T(ao)
        for (int el = 0; el < 16; el++) {
            int col = wbase + el * 4 + g;
            int s_ = sSnd[col], rc = sRcv[col];
            float wx = sVec[col * 3 + 0], wy = sVec[col * 3 + 1], wz = sVec[col * 3 + 2];
            float l2 = wx * wx + wy * wy + wz * wz;
            float il = (l2 > 0.f) ? rsqrtf(l2) : 0.f;
            float mx = T[f * 256 + (col ^ (2 * f))];
            int m = (c - 4) * 16 + f;
            const float* ev = up + (size_t)s_ * 256 + 64 + m * 3;
            float dot = ev[0] * wx + ev[1] * wy + ev[2] * wz;
            atomicAdd(agg + (size_t)rc * 512 + 64 + m, dot * il * mx);
        }
    }
    for (int c = 8; c < 12; c++) {
        float ao[16];
        COMPUTE_CHUNK(c, ao)
        WRITE_T(ao)
        for (int el = 0; el < 16; el++) {
            int col = wbase + el * 4 + g;
            int s_ = sSnd[col], rc = sRcv[col];
            float mx = T[f * 256 + (col ^ (2 * f))];
            int m = (c - 8) * 16 + f;
            const float* ev = up + (size_t)s_ * 256 + 64 + m * 3;
            float* ag = agg + (size_t)rc * 512 + 128 + m;
            atomicAdd(ag + 0,   ev[0] * mx);
            atomicAdd(ag + 64,  ev[1] * mx);
            atomicAdd(ag + 128, ev[2] * mx);
        }
    }
    for (int c = 12; c < 16; c++) {
        float ao[16];
        COMPUTE_CHUNK(c, ao)
        WRITE_T(ao)
        for (int el = 0; el < 16; el++) {
            int col = wbase + el * 4 + g;
            int s_ = sSnd[col], rc = sRcv[col];
            float wx = sVec[col * 3 + 0], wy = sVec[col * 3 + 1], wz = sVec[col * 3 + 2];
            float l2 = wx * wx + wy * wy + wz * wz;
            float il = (l2 > 0.f) ? rsqrtf(l2) : 0.f;
            float mx = T[f * 256 + (col ^ (2 * f))];
            int m = (c - 12) * 16 + f;
            float sc = up[(size_t)s_ * 256 + m] * 1.7320508075688772f * il * mx;
            float* ag = agg + (size_t)rc * 512 + 320 + m;
            atomicAdd(ag + 0,   sc * wx);
            atomicAdd(ag + 64,  sc * wy);
            atomicAdd(ag + 128, sc * wz);
        }
    }
    #undef COMPUTE_CHUNK
    #undef WRITE_T
}

extern "C" void kernel_launch(void* const* d_in, const int* in_sizes, int n_in,
                              void* d_out, int out_size, void* d_ws, size_t ws_size,
                              hipStream_t stream) {
    const float* vectors     = (const float*)d_in[0];
    const float* node_feats  = (const float*)d_in[1];
    const int*   node_specie = (const int*)d_in[2];
    const float* radial      = (const float*)d_in[3];
    const int*   senders     = (const int*)d_in[4];
    const int*   receivers   = (const int*)d_in[5];
    const float* W_up_s      = (const float*)d_in[6];
    const float* W_up_v      = (const float*)d_in[7];
    const float* mlp_w1      = (const float*)d_in[8];
    const float* mlp_w2      = (const float*)d_in[9];
    const float* mlp_w3      = (const float*)d_in[10];
    const float* mlp_wo      = (const float*)d_in[11];
    const float* W_skip_s    = (const float*)d_in[12];
    const float* W_skip_v    = (const float*)d_in[13];
    const float* W_down_s    = (const float*)d_in[14];
    const float* W_down_v    = (const float*)d_in[15];
    float* out = (float*)d_out;

    // workspace: up | agg-region (f32-sized, reused) | wpack | wp2
    float* up   = (float*)d_ws;                      // NN*256 f32  = 20.48 MB
    float* aggf = up + (size_t)NN * 256;             // NN*512 f32  = 40.96 MB (fallback)
    __half2* aggh = (__half2*)aggf;                  // NN*256 half2 (primary)
    uintptr_t wp_addr = ((uintptr_t)(aggf + (size_t)NN * 512) + 255) & ~(uintptr_t)255;
    f16* wpack = (f16*)wp_addr;                      // 52*64*8 f16 = 53.2 KB (26624 B, 256-mult)
    f16* wp2   = wpack + (size_t)52 * 64 * 8;        // 168*64*8 f16 = 172 KB
    size_t required = (size_t)((uintptr_t)(wp2 + (size_t)168 * 64 * 8)
                               - (uintptr_t)d_ws);

    if (ws_size >= required) {
        // ---- fused MFMA MLP + pk-fp16 scatter + MFMA node tail ----
        hipMemsetAsync(aggh, 0, (size_t)NN * 512 * sizeof(__half), stream);
        pack_kernel<<<13, 256, 0, stream>>>(mlp_w1, mlp_w2, mlp_w3, mlp_wo, wpack);
        pack2_kernel<<<42, 256, 0, stream>>>(W_down_s, W_down_v, W_skip_s, W_skip_v, wp2);
        up_kernel<<<NN / 16, 256, 0, stream>>>(node_feats, W_up_s, W_up_v, up, 1);
        mlp_scatter<<<EE / 64, 256, 0, stream>>>(radial, wpack,
            senders, receivers, vectors, up, aggh);
        node_mfma<<<(NN / 16 + 3) / 4, 256, 0, stream>>>(node_feats, node_specie,
            wp2, (const f16*)aggh, out);
    } else {
        // ---- fallback: round-3 fused atomic path (f32 agg) ----
        hipMemsetAsync(aggf, 0, (size_t)NN * 512 * sizeof(float), stream);
        up_kernel<<<NN / 16, 256, 0, stream>>>(node_feats, W_up_s, W_up_v, up, 0);
        edge_kernel_fb<<<EE / 256, 256, 0, stream>>>(
            vectors, radial, senders, receivers,
            mlp_w1, mlp_w2, mlp_w3, mlp_wo, up, aggf);
        node_kernel_f<<<NN / 16, 256, 0, stream>>>(node_feats, node_specie,
            W_down_s, W_down_v, W_skip_s, W_skip_v, aggf, out);
    }
}